// Round 15
// baseline (277.141 us; speedup 1.0000x reference)
//
#include <hip/hip_runtime.h>

typedef unsigned short u16;
typedef unsigned int u32;
typedef __attribute__((ext_vector_type(8))) __bf16 bf8v;    // MFMA A/B operand (8 bf16)
typedef __attribute__((ext_vector_type(8))) short s8v;      // same bits, for packing
typedef __attribute__((ext_vector_type(4))) float f4v;
typedef __attribute__((ext_vector_type(16))) float f16v;    // 32x32 MFMA C/D

#define DEV static __device__ __forceinline__

constexpr int NQ = 12544;   // B*H*W = 16*28*28
constexpr int MM = 8192;    // memory bank rows
constexpr int PP = 784;     // H*W
constexpr float EPSF = 1e-12f;

DEV u16 f2bf(float f) {  // RNE f32 -> bf16 (inputs are finite normals)
  u32 u = __float_as_uint(f);
  return (u16)((u + 0x7FFFu + ((u >> 16) & 1u)) >> 16);
}
DEV float bf2f(u16 h) { return __uint_as_float((u32)h << 16); }

DEV void gl2lds16(const u16* g, u16* l) {
  __builtin_amdgcn_global_load_lds(
      (const __attribute__((address_space(1))) unsigned int*)(g),
      (__attribute__((address_space(3))) unsigned int*)(l), 16, 0, 0);
}
DEV void gl2lds4(const float* g, float* l) {
  __builtin_amdgcn_global_load_lds(
      (const __attribute__((address_space(1))) unsigned int*)(g),
      (__attribute__((address_space(3))) unsigned int*)(l), 4, 0, 0);
}

template<int N> DEV void wait_vm() {   // counted vmcnt (T4): literal immediates only
  if constexpr (N == 0) asm volatile("s_waitcnt vmcnt(0)" ::: "memory");
  else if constexpr (N == 3) asm volatile("s_waitcnt vmcnt(3)" ::: "memory");
  else if constexpr (N == 5) asm volatile("s_waitcnt vmcnt(5)" ::: "memory");
  else if constexpr (N == 6) asm volatile("s_waitcnt vmcnt(6)" ::: "memory");
  else if constexpr (N == 10) asm volatile("s_waitcnt vmcnt(10)" ::: "memory");
  else static_assert(N == 0, "unsupported vmcnt");
}

// branchless sorted insert: keep 5 smallest in a0<=..<=a4
DEV void ins5(float v, float& a0, float& a1, float& a2, float& a3, float& a4) {
  float hi;
  hi = fmaxf(v, a0); a0 = fminf(v, a0); v = hi;
  hi = fmaxf(v, a1); a1 = fminf(v, a1); v = hi;
  hi = fmaxf(v, a2); a2 = fminf(v, a2); v = hi;
  hi = fmaxf(v, a3); a3 = fminf(v, a3); v = hi;
  a4 = fminf(v, a4);
}

// ================= fused prep =================
DEV void pack_bf16_dev(const float* __restrict__ x, u16* __restrict__ y, int bid, int tid) {
  int g = bid * 256 + tid;
  const float4* px = (const float4*)x + (size_t)g * 2;
  float4 a = px[0], b = px[1];
  s8v o;
  o[0] = (short)f2bf(a.x); o[1] = (short)f2bf(a.y); o[2] = (short)f2bf(a.z); o[3] = (short)f2bf(a.w);
  o[4] = (short)f2bf(b.x); o[5] = (short)f2bf(b.y); o[6] = (short)f2bf(b.z); o[7] = (short)f2bf(b.w);
  ((s8v*)y)[g] = o;
}

// mem pack: store -2*m (exact bf16 scale) K-MAJOR in global: yT[chunk][row][8]
template<int C>
DEV void pack_mem_dev(const float* __restrict__ x, u16* __restrict__ yT, float* __restrict__ nrm,
                      int bid, int tid) {
  int row = bid * 4 + (tid >> 6), lane = tid & 63;
  constexpr int E = C / 64;
  const float* src = x + (size_t)row * C + lane * E;
  float s = 0.f;
  if constexpr (E == 4) {
    float4 v = *(const float4*)src;
    s = v.x * v.x + v.y * v.y + v.z * v.z + v.w * v.w;
    u32 lo = (u32)f2bf(-2.f * v.x) | ((u32)f2bf(-2.f * v.y) << 16);
    u32 hi = (u32)f2bf(-2.f * v.z) | ((u32)f2bf(-2.f * v.w) << 16);
    size_t di = ((size_t)(lane >> 1) * MM + row) * 8 + (lane & 1) * 4;
    *(uint2*)(yT + di) = make_uint2(lo, hi);
  } else {
    float2 v = *(const float2*)src;
    s = v.x * v.x + v.y * v.y;
    size_t di = ((size_t)(lane >> 2) * MM + row) * 8 + (lane & 3) * 2;
    *(u32*)(yT + di) = (u32)f2bf(-2.f * v.x) | ((u32)f2bf(-2.f * v.y) << 16);
  }
#pragma unroll
  for (int m = 1; m < 64; m <<= 1) s += __shfl_xor(s, m);
  if (lane == 0) nrm[row] = s;
}

template<int C>
DEV void pack_q_dev(const float* __restrict__ q, u16* __restrict__ qfb, int bid, int tid) {
  int g = bid * 256 + tid;
  int n = g % NQ;
  int cc = g / NQ;
  int b = n / PP, p = n % PP;
  int c0 = cc * 8;
  const float* src = q + ((size_t)b * C + c0) * PP + p;
  s8v o;
#pragma unroll
  for (int i = 0; i < 8; ++i) o[i] = (short)f2bf(src[(size_t)i * PP]);
  ((s8v*)qfb)[((size_t)n * C + c0) >> 3] = o;
}

__global__ __launch_bounds__(256) void k_prep(
    const float* __restrict__ q2, const float* __restrict__ q3,
    const float* __restrict__ mem2, const float* __restrict__ mem3,
    const float* __restrict__ icov2, const float* __restrict__ icov3,
    u16* __restrict__ qf2b, u16* __restrict__ qf3b,
    u16* __restrict__ m2t, u16* __restrict__ m3t,
    u16* __restrict__ ic2b, u16* __restrict__ ic3b,
    float* __restrict__ mn2, float* __restrict__ mn3) {
  int bid = blockIdx.x, tid = threadIdx.x;
  if (bid < 2048)       pack_mem_dev<128>(mem2, m2t, mn2, bid, tid);
  else if (bid < 4096)  pack_mem_dev<256>(mem3, m3t, mn3, bid - 2048, tid);
  else if (bid < 4104)  pack_bf16_dev(icov2, ic2b, bid - 4096, tid);
  else if (bid < 4136)  pack_bf16_dev(icov3, ic3b, bid - 4104, tid);
  else if (bid < 4920)  pack_q_dev<128>(q2, qf2b, bid - 4136, tid);
  else                  pack_q_dev<256>(q3, qf3b, bid - 4920, tid);
}

// ================= fused distances + per-row 5 smallest d2' =================
// R14 shell (best measured) + VALU cuts: persistent staging pointers (no per-tile
// 64-bit addr recompute), setprio around MFMA cluster (T5), 3 blocks/CU occupancy.
template<int C, int NSPLIT>
DEV void score_body(const u16* __restrict__ qf, const u16* __restrict__ memT,
                    const float* __restrict__ mn, float* __restrict__ kp,
                    float* __restrict__ qn,
                    int bid2, u16* __restrict__ BsB, float* __restrict__ mnSB, int tid) {
  constexpr int MT = 32, MS = MM / NSPLIT, NT = MS / MT;   // NT = 32
  constexpr int CHUNKS = C / 8;           // 16B chunks per mem row (32 / 16)
  constexpr int PAIRS = CHUNKS / 2;       // K-groups of 16 elems (16 / 8)
  constexpr int SIT = PAIRS / 4;          // gl2lds16 per wave per tile (4 / 2)
  constexpr int P = SIT + 1;              // + mn load (5 / 3)
  constexpr int BSTRIDE = 8192;           // u16 per LDS buffer (16KB, sized for C=256)
  constexpr int QROWS = 4 * 64;           // 4 waves x 64 q-cols = 256
  constexpr int RT = NQ / QROWS;          // 49 exactly
  static_assert(NT >= 4, "pipeline needs NT>=4");

  const int wave = tid >> 6, lane = tid & 63;
  const int l31 = lane & 31, kh = lane >> 5;
  const int rt = bid2 % RT, split = bid2 / RT;   // split-major: same-split blocks cluster (L2)
  const int row0 = rt * QROWS, mb0 = split * MS;

  // q fragments (B operand; loop-invariant) -> registers, pinned. 2 col-groups.
  bf8v qv[2][PAIRS];
#pragma unroll
  for (int cg = 0; cg < 2; ++cg)
#pragma unroll
    for (int kk = 0; kk < PAIRS; ++kk)
      qv[cg][kk] = *(const bf8v*)(qf + (size_t)(row0 + wave * 64 + cg * 32 + l31) * C + kk * 16 + kh * 8);
#pragma unroll
  for (int cg = 0; cg < 2; ++cg)
#pragma unroll
    for (int kk = 0; kk < PAIRS; ++kk)
      asm volatile("" : "+v"(qv[cg][kk]));

  // free q-norm: lane holds K-half kh of q-rows (row0+wave*64+cg*32+l31)
  if (split == 0) {
#pragma unroll
    for (int cg = 0; cg < 2; ++cg) {
      float s = 0.f;
#pragma unroll
      for (int kk = 0; kk < PAIRS; ++kk)
#pragma unroll
        for (int i = 0; i < 8; ++i) { float v = (float)qv[cg][kk][i]; s = fmaf(v, v, s); }
      s += __shfl_xor(s, 32);
      if (lane < 32) qn[row0 + wave * 64 + cg * 32 + l31] = s;
    }
  }

  // persistent staging pointers: advance by +MT rows (+256 u16 / +32 floats) per call
  const u16* mptr[SIT];
  u32 ldsoff[SIT];
#pragma unroll
  for (int it = 0; it < SIT; ++it) {
    int cp2 = wave + it * 4;
    mptr[it] = memT + ((size_t)(cp2 * 2 + kh) * MM + mb0 + l31) * 8;
    ldsoff[it] = (u32)(cp2 * 512 + lane * 8);
  }
  const float* nptr = mn + mb0 + (lane & 31);
  const u32 nldsoff = (u32)(lane & 31);

  auto STAGE = [&](int buf) {   // exactly P vmem ops per wave; t implicit (sequential calls)
    u16* Bs = BsB + buf * BSTRIDE;
#pragma unroll
    for (int it = 0; it < SIT; ++it) {
      gl2lds16(mptr[it], Bs + ldsoff[it]);
      mptr[it] += MT * 8;
    }
    gl2lds4(nptr, mnSB + buf * 64 + nldsoff);
    nptr += MT;
  };

  float t5[2][5];
#pragma unroll
  for (int cg = 0; cg < 2; ++cg)
#pragma unroll
    for (int i = 0; i < 5; ++i) t5[cg][i] = 1e30f;

  auto COMPUTE = [&](int cur) {
    f16v acc[2];
#pragma unroll
    for (int g = 0; g < 4; ++g) {
      f4v m4 = *(const f4v*)(mnSB + cur * 64 + g * 8 + kh * 4);
#pragma unroll
      for (int cg = 0; cg < 2; ++cg) {
        acc[cg][4 * g + 0] = m4[0]; acc[cg][4 * g + 1] = m4[1];
        acc[cg][4 * g + 2] = m4[2]; acc[cg][4 * g + 3] = m4[3];
      }
    }
    const u16* Bb = BsB + cur * BSTRIDE + l31 * 8 + kh * 256;
    __builtin_amdgcn_s_setprio(1);
#pragma unroll
    for (int kk = 0; kk < PAIRS; ++kk) {
      bf8v mf = *(const bf8v*)(Bb + kk * 512);
      acc[0] = __builtin_amdgcn_mfma_f32_32x32x16_bf16(mf, qv[0][kk], acc[0], 0, 0, 0);
      acc[1] = __builtin_amdgcn_mfma_f32_32x32x16_bf16(mf, qv[1][kk], acc[1], 0, 0, 0);
    }
    __builtin_amdgcn_s_setprio(0);
#pragma unroll
    for (int cg = 0; cg < 2; ++cg)
#pragma unroll
      for (int g = 0; g < 4; ++g) {
        float c0 = acc[cg][4 * g + 0], c1 = acc[cg][4 * g + 1];
        float c2 = acc[cg][4 * g + 2], c3 = acc[cg][4 * g + 3];
        float m01 = fminf(fminf(c0, c1), fminf(c2, c3));
        if (m01 < t5[cg][4]) {
          ins5(c0, t5[cg][0], t5[cg][1], t5[cg][2], t5[cg][3], t5[cg][4]);
          ins5(c1, t5[cg][0], t5[cg][1], t5[cg][2], t5[cg][3], t5[cg][4]);
          ins5(c2, t5[cg][0], t5[cg][1], t5[cg][2], t5[cg][3], t5[cg][4]);
          ins5(c3, t5[cg][0], t5[cg][1], t5[cg][2], t5[cg][3], t5[cg][4]);
        }
      }
  };

  STAGE(0); STAGE(1); STAGE(2);   // tiles 0..2 in flight (3P outstanding)

  for (int t = 0; t < NT - 3; ++t) {
    const int cur = t % 3;
    wait_vm<2 * P>();
    __builtin_amdgcn_sched_barrier(0);
    __builtin_amdgcn_s_barrier();
    __builtin_amdgcn_sched_barrier(0);
    COMPUTE(cur);
    __builtin_amdgcn_sched_barrier(0);
    __builtin_amdgcn_s_barrier();      // all waves done reading Bs[cur]
    __builtin_amdgcn_sched_barrier(0);
    STAGE(cur);                        // tile t+3 into freed buffer
  }
  {
    wait_vm<2 * P>();
    __builtin_amdgcn_sched_barrier(0);
    __builtin_amdgcn_s_barrier();
    __builtin_amdgcn_sched_barrier(0);
    COMPUTE((NT - 3) % 3);
    __builtin_amdgcn_sched_barrier(0);
    __builtin_amdgcn_s_barrier();
    wait_vm<P>();
    __builtin_amdgcn_sched_barrier(0);
    __builtin_amdgcn_s_barrier();
    __builtin_amdgcn_sched_barrier(0);
    COMPUTE((NT - 2) % 3);
    __builtin_amdgcn_sched_barrier(0);
    __builtin_amdgcn_s_barrier();
    wait_vm<0>();
    __builtin_amdgcn_sched_barrier(0);
    __builtin_amdgcn_s_barrier();
    __builtin_amdgcn_sched_barrier(0);
    COMPUTE((NT - 1) % 3);
  }

  // per cg: merge the 2 lanes holding the same q-col (lane, lane+32), write
#pragma unroll
  for (int cg = 0; cg < 2; ++cg) {
    float r0 = __shfl_xor(t5[cg][0], 32), r1 = __shfl_xor(t5[cg][1], 32),
          r2 = __shfl_xor(t5[cg][2], 32), r3 = __shfl_xor(t5[cg][3], 32),
          r4 = __shfl_xor(t5[cg][4], 32);
    ins5(r0, t5[cg][0], t5[cg][1], t5[cg][2], t5[cg][3], t5[cg][4]);
    ins5(r1, t5[cg][0], t5[cg][1], t5[cg][2], t5[cg][3], t5[cg][4]);
    ins5(r2, t5[cg][0], t5[cg][1], t5[cg][2], t5[cg][3], t5[cg][4]);
    ins5(r3, t5[cg][0], t5[cg][1], t5[cg][2], t5[cg][3], t5[cg][4]);
    ins5(r4, t5[cg][0], t5[cg][1], t5[cg][2], t5[cg][3], t5[cg][4]);
    if (lane < 32) {
      int grow = row0 + wave * 64 + cg * 32 + l31;
      float* o = kp + ((size_t)grow * NSPLIT + split) * 5;
      o[0] = t5[cg][0]; o[1] = t5[cg][1]; o[2] = t5[cg][2]; o[3] = t5[cg][3]; o[4] = t5[cg][4];
    }
  }
}

// fused launcher: even bid -> C=256 (layer 3), odd bid -> C=128 (layer 2)
__global__ __launch_bounds__(256, 3) void k_score_f(
    const u16* __restrict__ qf3, const u16* __restrict__ m3t,
    const float* __restrict__ mn3, float* __restrict__ kp3, float* __restrict__ qn3,
    const u16* __restrict__ qf2, const u16* __restrict__ m2t,
    const float* __restrict__ mn2, float* __restrict__ kp2, float* __restrict__ qn2) {
  __shared__ alignas(16) u16 Bs[3 * 8192];
  __shared__ alignas(16) float mnS[3 * 64];
  int bid = blockIdx.x, tid = threadIdx.x;
  if (bid & 1) score_body<128, 8>(qf2, m2t, mn2, kp2, qn2, bid >> 1, Bs, mnS, tid);
  else         score_body<256, 8>(qf3, m3t, mn3, kp3, qn3, bid >> 1, Bs, mnS, tid);
}

// ================= Mahalanobis only (q-norms computed in k_score_f) =================
template<int C>
DEV void maha_dev(const u16* __restrict__ qfb, const float* __restrict__ mu,
                  const u16* __restrict__ icovb, float* __restrict__ mh,
                  u16* As, float* muS, int bid, int tid) {
  constexpr int QT = 64, KCH = C / 8;
  int wave = tid >> 6, lane = tid & 63;
  int row0 = bid * QT;

  for (int i = tid; i < C; i += 256) muS[i] = mu[i];
  __syncthreads();
  for (int u = tid; u < QT * KCH; u += 256) {
    int r = u / KCH, cc = u % KCH;
    bf8v v = *(const bf8v*)(qfb + (size_t)(row0 + r) * C + cc * 8);
    s8v d;
#pragma unroll
    for (int i = 0; i < 8; ++i) d[i] = (short)f2bf((float)v[i] - muS[cc * 8 + i]);
    *(s8v*)(As + r * C + ((cc ^ (r & 7)) << 3)) = d;
  }
  __syncthreads();

  int arow = wave * 16 + (lane & 15);
  int kb = lane >> 4;
  float mm[4] = {0.f, 0.f, 0.f, 0.f};
#pragma unroll
  for (int cb = 0; cb < C / 16; ++cb) {
    f4v acc = (f4v){0.f, 0.f, 0.f, 0.f};
    int bcol = cb * 16 + (lane & 15);
#pragma unroll
    for (int kk = 0; kk < C / 32; ++kk) {
      int kc = kk * 4 + kb;
      bf8v a = *(const bf8v*)(As + arow * C + ((kc ^ (arow & 7)) << 3));
      bf8v b = *(const bf8v*)(icovb + (size_t)bcol * C + kc * 8);
      acc = __builtin_amdgcn_mfma_f32_16x16x32_bf16(a, b, acc, 0, 0, 0);
    }
#pragma unroll
    for (int r = 0; r < 4; ++r) {
      int row = wave * 16 + (lane >> 4) * 4 + r;
      int col = cb * 16 + (lane & 15);
      float dv = bf2f(As[row * C + (((col >> 3) ^ (row & 7)) << 3) + (col & 7)]);
      mm[r] += acc[r] * dv;
    }
  }
#pragma unroll
  for (int r = 0; r < 4; ++r) {
    float v = mm[r];
    v += __shfl_xor(v, 1); v += __shfl_xor(v, 2);
    v += __shfl_xor(v, 4); v += __shfl_xor(v, 8);
    if ((lane & 15) == 0)
      mh[row0 + wave * 16 + (lane >> 4) * 4 + r] = sqrtf(fmaxf(v, EPSF));
  }
}

__global__ __launch_bounds__(256) void k_maha(
    const u16* __restrict__ qf2b, const u16* __restrict__ qf3b,
    const float* __restrict__ mean2, const float* __restrict__ mean3,
    const u16* __restrict__ ic2b, const u16* __restrict__ ic3b,
    float* __restrict__ mh2, float* __restrict__ mh3) {
  __shared__ alignas(16) u16 As[64 * 256];
  __shared__ float muS[256];
  int bid = blockIdx.x, tid = threadIdx.x;
  if (bid < 196) maha_dev<128>(qf2b, mean2, ic2b, mh2, As, muS, bid, tid);
  else           maha_dev<256>(qf3b, mean3, ic3b, mh3, As, muS, bid - 196, tid);
}

// ================= combine: merge knn splits (+qn), build maps =================
template<int S>
DEV float knn_merge(const float* kp, int n, float qv) {
  float t0 = 1e30f, t1 = 1e30f, t2 = 1e30f, t3 = 1e30f, t4 = 1e30f;
  const float* p = kp + (size_t)n * S * 5;
#pragma unroll
  for (int i = 0; i < S * 5; ++i) ins5(p[i], t0, t1, t2, t3, t4);
  return 0.2f * (sqrtf(fmaxf(t0 + qv, EPSF)) + sqrtf(fmaxf(t1 + qv, EPSF)) +
                 sqrtf(fmaxf(t2 + qv, EPSF)) + sqrtf(fmaxf(t3 + qv, EPSF)) +
                 sqrtf(fmaxf(t4 + qv, EPSF)));
}

__global__ __launch_bounds__(256) void k_combine(
    const float* __restrict__ kp2, const float* __restrict__ kp3,
    const float* __restrict__ qn2, const float* __restrict__ qn3,
    const float* __restrict__ mh2, const float* __restrict__ mh3,
    float* __restrict__ out) {
  int n = blockIdx.x * 256 + threadIdx.x;
  float m2v = 0.5f * (knn_merge<8>(kp2, n, qn2[n]) + mh2[n]);
  float m3v = 0.5f * (knn_merge<8>(kp3, n, qn3[n]) + mh3[n]);
  out[16 + n] = 0.5f * (m2v + m3v);
  out[16 + NQ + n] = m2v;
  out[16 + 2 * NQ + n] = m3v;
}

// ================= per-image top-10 mean over 784-pixel map =================
__global__ __launch_bounds__(256) void k_top10(const float* __restrict__ comb, float* __restrict__ pred) {
  __shared__ float vals[1024];
  __shared__ float rv[256];
  __shared__ int ri[256];
  __shared__ float ssum;
  int b = blockIdx.x, tid = threadIdx.x;
  for (int i = tid; i < 1024; i += 256) vals[i] = (i < PP) ? comb[b * PP + i] : -1e30f;
  if (tid == 0) ssum = 0.f;
  __syncthreads();
  for (int it = 0; it < 10; ++it) {
    float bv = -1e30f; int bi = 0;
    for (int i = tid; i < 1024; i += 256) { float v = vals[i]; if (v > bv) { bv = v; bi = i; } }
    rv[tid] = bv; ri[tid] = bi;
    __syncthreads();
    for (int s = 128; s; s >>= 1) {
      if (tid < s && rv[tid + s] > rv[tid]) { rv[tid] = rv[tid + s]; ri[tid] = ri[tid + s]; }
      __syncthreads();
    }
    if (tid == 0) { ssum += rv[0]; vals[ri[0]] = -1e30f; }
    __syncthreads();
  }
  if (tid == 0) pred[b] = ssum * 0.1f;
}

extern "C" void kernel_launch(void* const* d_in, const int* in_sizes, int n_in,
                              void* d_out, int out_size, void* d_ws, size_t ws_size,
                              hipStream_t stream) {
  const float* q2    = (const float*)d_in[0];
  const float* q3    = (const float*)d_in[1];
  const float* mem2  = (const float*)d_in[2];
  const float* mem3  = (const float*)d_in[3];
  const float* mean2 = (const float*)d_in[4];
  const float* mean3 = (const float*)d_in[5];
  const float* icov2 = (const float*)d_in[6];
  const float* icov3 = (const float*)d_in[7];
  float* out = (float*)d_out;

  char* w = (char*)d_ws;
  auto alloc = [&](size_t bytes) { void* p = (void*)w; w += (bytes + 255) & ~(size_t)255; return p; };
  u16* qf2b = (u16*)alloc((size_t)NQ * 128 * 2);
  u16* qf3b = (u16*)alloc((size_t)NQ * 256 * 2);
  u16* m2t  = (u16*)alloc((size_t)MM * 128 * 2);
  u16* m3t  = (u16*)alloc((size_t)MM * 256 * 2);
  u16* ic2b = (u16*)alloc((size_t)128 * 128 * 2);
  u16* ic3b = (u16*)alloc((size_t)256 * 256 * 2);
  float* qn2 = (float*)alloc((size_t)NQ * 4);
  float* qn3 = (float*)alloc((size_t)NQ * 4);
  float* mn2 = (float*)alloc((size_t)MM * 4);
  float* mn3 = (float*)alloc((size_t)MM * 4);
  float* kp2 = (float*)alloc((size_t)NQ * 8 * 5 * 4);
  float* kp3 = (float*)alloc((size_t)NQ * 8 * 5 * 4);
  float* mh2 = (float*)alloc((size_t)NQ * 4);
  float* mh3 = (float*)alloc((size_t)NQ * 4);

  k_prep<<<6488, 256, 0, stream>>>(q2, q3, mem2, mem3, icov2, icov3,
                                   qf2b, qf3b, m2t, m3t, ic2b, ic3b, mn2, mn3);

  // fused score (+q-norms): 392 C=256 (even bid) + 392 C=128 (odd bid), 256-thr blocks
  k_score_f<<<784, 256, 0, stream>>>(qf3b, m3t, mn3, kp3, qn3, qf2b, m2t, mn2, kp2, qn2);

  k_maha<<<392, 256, 0, stream>>>(qf2b, qf3b, mean2, mean3, ic2b, ic3b, mh2, mh3);

  k_combine<<<NQ / 256, 256, 0, stream>>>(kp2, kp3, qn2, qn3, mh2, mh3, out);
  k_top10<<<16, 256, 0, stream>>>(out + 16, out);

  (void)in_sizes; (void)n_in; (void)out_size; (void)ws_size;
}

// Round 16
// 182.446 us; speedup vs baseline: 1.5190x; 1.5190x over previous
//
#include <hip/hip_runtime.h>

typedef unsigned short u16;
typedef unsigned int u32;
typedef __attribute__((ext_vector_type(8))) __bf16 bf8v;    // MFMA A/B operand (8 bf16)
typedef __attribute__((ext_vector_type(8))) short s8v;      // same bits, for packing
typedef __attribute__((ext_vector_type(4))) float f4v;
typedef __attribute__((ext_vector_type(16))) float f16v;    // 32x32 MFMA C/D

#define DEV static __device__ __forceinline__

constexpr int NQ = 12544;   // B*H*W = 16*28*28
constexpr int MM = 8192;    // memory bank rows
constexpr int PP = 784;     // H*W
constexpr float EPSF = 1e-12f;

DEV u16 f2bf(float f) {  // RNE f32 -> bf16 (inputs are finite normals)
  u32 u = __float_as_uint(f);
  return (u16)((u + 0x7FFFu + ((u >> 16) & 1u)) >> 16);
}
DEV float bf2f(u16 h) { return __uint_as_float((u32)h << 16); }

DEV void gl2lds16(const u16* g, u16* l) {
  __builtin_amdgcn_global_load_lds(
      (const __attribute__((address_space(1))) unsigned int*)(g),
      (__attribute__((address_space(3))) unsigned int*)(l), 16, 0, 0);
}
DEV void gl2lds4(const float* g, float* l) {
  __builtin_amdgcn_global_load_lds(
      (const __attribute__((address_space(1))) unsigned int*)(g),
      (__attribute__((address_space(3))) unsigned int*)(l), 4, 0, 0);
}

template<int N> DEV void wait_vm() {   // counted vmcnt (T4): literal immediates only
  if constexpr (N == 0) asm volatile("s_waitcnt vmcnt(0)" ::: "memory");
  else if constexpr (N == 3) asm volatile("s_waitcnt vmcnt(3)" ::: "memory");
  else if constexpr (N == 5) asm volatile("s_waitcnt vmcnt(5)" ::: "memory");
  else if constexpr (N == 6) asm volatile("s_waitcnt vmcnt(6)" ::: "memory");
  else if constexpr (N == 10) asm volatile("s_waitcnt vmcnt(10)" ::: "memory");
  else static_assert(N == 0, "unsupported vmcnt");
}

// branchless sorted insert: keep 5 smallest in a0<=..<=a4
DEV void ins5(float v, float& a0, float& a1, float& a2, float& a3, float& a4) {
  float hi;
  hi = fmaxf(v, a0); a0 = fminf(v, a0); v = hi;
  hi = fmaxf(v, a1); a1 = fminf(v, a1); v = hi;
  hi = fmaxf(v, a2); a2 = fminf(v, a2); v = hi;
  hi = fmaxf(v, a3); a3 = fminf(v, a3); v = hi;
  a4 = fminf(v, a4);
}

// ================= fused prep =================
DEV void pack_bf16_dev(const float* __restrict__ x, u16* __restrict__ y, int bid, int tid) {
  int g = bid * 256 + tid;
  const float4* px = (const float4*)x + (size_t)g * 2;
  float4 a = px[0], b = px[1];
  s8v o;
  o[0] = (short)f2bf(a.x); o[1] = (short)f2bf(a.y); o[2] = (short)f2bf(a.z); o[3] = (short)f2bf(a.w);
  o[4] = (short)f2bf(b.x); o[5] = (short)f2bf(b.y); o[6] = (short)f2bf(b.z); o[7] = (short)f2bf(b.w);
  ((s8v*)y)[g] = o;
}

// mem pack: store -2*m (exact bf16 scale) K-MAJOR in global: yT[chunk][row][8]
template<int C>
DEV void pack_mem_dev(const float* __restrict__ x, u16* __restrict__ yT, float* __restrict__ nrm,
                      int bid, int tid) {
  int row = bid * 4 + (tid >> 6), lane = tid & 63;
  constexpr int E = C / 64;
  const float* src = x + (size_t)row * C + lane * E;
  float s = 0.f;
  if constexpr (E == 4) {
    float4 v = *(const float4*)src;
    s = v.x * v.x + v.y * v.y + v.z * v.z + v.w * v.w;
    u32 lo = (u32)f2bf(-2.f * v.x) | ((u32)f2bf(-2.f * v.y) << 16);
    u32 hi = (u32)f2bf(-2.f * v.z) | ((u32)f2bf(-2.f * v.w) << 16);
    size_t di = ((size_t)(lane >> 1) * MM + row) * 8 + (lane & 1) * 4;
    *(uint2*)(yT + di) = make_uint2(lo, hi);
  } else {
    float2 v = *(const float2*)src;
    s = v.x * v.x + v.y * v.y;
    size_t di = ((size_t)(lane >> 2) * MM + row) * 8 + (lane & 3) * 2;
    *(u32*)(yT + di) = (u32)f2bf(-2.f * v.x) | ((u32)f2bf(-2.f * v.y) << 16);
  }
#pragma unroll
  for (int m = 1; m < 64; m <<= 1) s += __shfl_xor(s, m);
  if (lane == 0) nrm[row] = s;
}

template<int C>
DEV void pack_q_dev(const float* __restrict__ q, u16* __restrict__ qfb, int bid, int tid) {
  int g = bid * 256 + tid;
  int n = g % NQ;
  int cc = g / NQ;
  int b = n / PP, p = n % PP;
  int c0 = cc * 8;
  const float* src = q + ((size_t)b * C + c0) * PP + p;
  s8v o;
#pragma unroll
  for (int i = 0; i < 8; ++i) o[i] = (short)f2bf(src[(size_t)i * PP]);
  ((s8v*)qfb)[((size_t)n * C + c0) >> 3] = o;
}

__global__ __launch_bounds__(256) void k_prep(
    const float* __restrict__ q2, const float* __restrict__ q3,
    const float* __restrict__ mem2, const float* __restrict__ mem3,
    const float* __restrict__ icov2, const float* __restrict__ icov3,
    u16* __restrict__ qf2b, u16* __restrict__ qf3b,
    u16* __restrict__ m2t, u16* __restrict__ m3t,
    u16* __restrict__ ic2b, u16* __restrict__ ic3b,
    float* __restrict__ mn2, float* __restrict__ mn3) {
  int bid = blockIdx.x, tid = threadIdx.x;
  if (bid < 2048)       pack_mem_dev<128>(mem2, m2t, mn2, bid, tid);
  else if (bid < 4096)  pack_mem_dev<256>(mem3, m3t, mn3, bid - 2048, tid);
  else if (bid < 4104)  pack_bf16_dev(icov2, ic2b, bid - 4096, tid);
  else if (bid < 4136)  pack_bf16_dev(icov3, ic3b, bid - 4104, tid);
  else if (bid < 4920)  pack_q_dev<128>(q2, qf2b, bid - 4136, tid);
  else                  pack_q_dev<256>(q3, qf3b, bid - 4920, tid);
}

// ================= fused distances + per-row 5 smallest d2' =================
// R14 body (best measured): CG=2 (one A-frag ds_read feeds two MFMAs / two acc
// chains), 4-wave blocks, 3-buffer counted-vmcnt pipeline, in-register top-5.
template<int C, int NSPLIT>
DEV void score_body(const u16* __restrict__ qf, const u16* __restrict__ memT,
                    const float* __restrict__ mn, float* __restrict__ kp,
                    float* __restrict__ qn,
                    int bid2, u16* __restrict__ BsB, float* __restrict__ mnSB, int tid) {
  constexpr int MT = 32, MS = MM / NSPLIT, NT = MS / MT;   // NT = 32
  constexpr int CHUNKS = C / 8;           // 16B chunks per mem row (32 / 16)
  constexpr int PAIRS = CHUNKS / 2;       // K-groups of 16 elems (16 / 8)
  constexpr int SIT = PAIRS / 4;          // gl2lds16 per wave per tile (4 / 2)
  constexpr int P = SIT + 1;              // + mn load (5 / 3)
  constexpr int BSTRIDE = 8192;           // u16 per LDS buffer (16KB, sized for C=256)
  constexpr int QROWS = 4 * 64;           // 4 waves x 64 q-cols = 256
  constexpr int RT = NQ / QROWS;          // 49 exactly
  static_assert(NT >= 4, "pipeline needs NT>=4");

  const int wave = tid >> 6, lane = tid & 63;
  const int l31 = lane & 31, kh = lane >> 5;
  const int rt = bid2 % RT, split = bid2 / RT;
  const int row0 = rt * QROWS, mb0 = split * MS;

  // q fragments (B operand; loop-invariant) -> registers, pinned. 2 col-groups.
  bf8v qv[2][PAIRS];
#pragma unroll
  for (int cg = 0; cg < 2; ++cg)
#pragma unroll
    for (int kk = 0; kk < PAIRS; ++kk)
      qv[cg][kk] = *(const bf8v*)(qf + (size_t)(row0 + wave * 64 + cg * 32 + l31) * C + kk * 16 + kh * 8);
#pragma unroll
  for (int cg = 0; cg < 2; ++cg)
#pragma unroll
    for (int kk = 0; kk < PAIRS; ++kk)
      asm volatile("" : "+v"(qv[cg][kk]));

  // free q-norm: lane holds K-half kh of q-rows (row0+wave*64+cg*32+l31)
  if (split == 0) {
#pragma unroll
    for (int cg = 0; cg < 2; ++cg) {
      float s = 0.f;
#pragma unroll
      for (int kk = 0; kk < PAIRS; ++kk)
#pragma unroll
        for (int i = 0; i < 8; ++i) { float v = (float)qv[cg][kk][i]; s = fmaf(v, v, s); }
      s += __shfl_xor(s, 32);
      if (lane < 32) qn[row0 + wave * 64 + cg * 32 + l31] = s;
    }
  }

  auto STAGE = [&](int buf, int t) {   // exactly P vmem ops per wave
    const int mrow0 = mb0 + t * MT;
    u16* Bs = BsB + buf * BSTRIDE;
#pragma unroll
    for (int it = 0; it < SIT; ++it) {
      int cp2 = wave + it * 4;
      gl2lds16(memT + ((size_t)(cp2 * 2 + kh) * MM + mrow0 + l31) * 8,
               Bs + cp2 * 512 + lane * 8);
    }
    gl2lds4(mn + mrow0 + (lane & 31), mnSB + buf * 64 + (lane & 31));   // dup: benign
  };

  float t5[2][5];
#pragma unroll
  for (int cg = 0; cg < 2; ++cg)
#pragma unroll
    for (int i = 0; i < 5; ++i) t5[cg][i] = 1e30f;

  auto COMPUTE = [&](int cur) {
    f16v acc[2];
#pragma unroll
    for (int g = 0; g < 4; ++g) {
      f4v m4 = *(const f4v*)(mnSB + cur * 64 + g * 8 + kh * 4);
#pragma unroll
      for (int cg = 0; cg < 2; ++cg) {
        acc[cg][4 * g + 0] = m4[0]; acc[cg][4 * g + 1] = m4[1];
        acc[cg][4 * g + 2] = m4[2]; acc[cg][4 * g + 3] = m4[3];
      }
    }
    const u16* Bb = BsB + cur * BSTRIDE + l31 * 8 + kh * 256;
#pragma unroll
    for (int kk = 0; kk < PAIRS; ++kk) {
      bf8v mf = *(const bf8v*)(Bb + kk * 512);
      acc[0] = __builtin_amdgcn_mfma_f32_32x32x16_bf16(mf, qv[0][kk], acc[0], 0, 0, 0);
      acc[1] = __builtin_amdgcn_mfma_f32_32x32x16_bf16(mf, qv[1][kk], acc[1], 0, 0, 0);
    }
#pragma unroll
    for (int cg = 0; cg < 2; ++cg)
#pragma unroll
      for (int g = 0; g < 4; ++g) {
        float c0 = acc[cg][4 * g + 0], c1 = acc[cg][4 * g + 1];
        float c2 = acc[cg][4 * g + 2], c3 = acc[cg][4 * g + 3];
        float m01 = fminf(fminf(c0, c1), fminf(c2, c3));
        if (m01 < t5[cg][4]) {
          ins5(c0, t5[cg][0], t5[cg][1], t5[cg][2], t5[cg][3], t5[cg][4]);
          ins5(c1, t5[cg][0], t5[cg][1], t5[cg][2], t5[cg][3], t5[cg][4]);
          ins5(c2, t5[cg][0], t5[cg][1], t5[cg][2], t5[cg][3], t5[cg][4]);
          ins5(c3, t5[cg][0], t5[cg][1], t5[cg][2], t5[cg][3], t5[cg][4]);
        }
      }
  };

  STAGE(0, 0); STAGE(1, 1); STAGE(2, 2);   // 3 tiles in flight (3P outstanding)

  for (int t = 0; t < NT - 3; ++t) {
    const int cur = t % 3;
    wait_vm<2 * P>();
    __builtin_amdgcn_sched_barrier(0);
    __builtin_amdgcn_s_barrier();
    __builtin_amdgcn_sched_barrier(0);
    COMPUTE(cur);
    __builtin_amdgcn_sched_barrier(0);
    __builtin_amdgcn_s_barrier();      // all waves done reading Bs[cur]
    __builtin_amdgcn_sched_barrier(0);
    STAGE(cur, t + 3);
  }
  {
    wait_vm<2 * P>();
    __builtin_amdgcn_sched_barrier(0);
    __builtin_amdgcn_s_barrier();
    __builtin_amdgcn_sched_barrier(0);
    COMPUTE((NT - 3) % 3);
    __builtin_amdgcn_sched_barrier(0);
    __builtin_amdgcn_s_barrier();
    wait_vm<P>();
    __builtin_amdgcn_sched_barrier(0);
    __builtin_amdgcn_s_barrier();
    __builtin_amdgcn_sched_barrier(0);
    COMPUTE((NT - 2) % 3);
    __builtin_amdgcn_sched_barrier(0);
    __builtin_amdgcn_s_barrier();
    wait_vm<0>();
    __builtin_amdgcn_sched_barrier(0);
    __builtin_amdgcn_s_barrier();
    __builtin_amdgcn_sched_barrier(0);
    COMPUTE((NT - 1) % 3);
  }

  // per cg: merge the 2 lanes holding the same q-col (lane, lane+32), write
#pragma unroll
  for (int cg = 0; cg < 2; ++cg) {
    float r0 = __shfl_xor(t5[cg][0], 32), r1 = __shfl_xor(t5[cg][1], 32),
          r2 = __shfl_xor(t5[cg][2], 32), r3 = __shfl_xor(t5[cg][3], 32),
          r4 = __shfl_xor(t5[cg][4], 32);
    ins5(r0, t5[cg][0], t5[cg][1], t5[cg][2], t5[cg][3], t5[cg][4]);
    ins5(r1, t5[cg][0], t5[cg][1], t5[cg][2], t5[cg][3], t5[cg][4]);
    ins5(r2, t5[cg][0], t5[cg][1], t5[cg][2], t5[cg][3], t5[cg][4]);
    ins5(r3, t5[cg][0], t5[cg][1], t5[cg][2], t5[cg][3], t5[cg][4]);
    ins5(r4, t5[cg][0], t5[cg][1], t5[cg][2], t5[cg][3], t5[cg][4]);
    if (lane < 32) {
      int grow = row0 + wave * 64 + cg * 32 + l31;
      float* o = kp + ((size_t)grow * NSPLIT + split) * 5;
      o[0] = t5[cg][0]; o[1] = t5[cg][1]; o[2] = t5[cg][2]; o[3] = t5[cg][3]; o[4] = t5[cg][4];
    }
  }
}

// ================= Mahalanobis body (co-dispatched with score) =================
template<int C>
DEV void maha_dev(const u16* __restrict__ qfb, const float* __restrict__ mu,
                  const u16* __restrict__ icovb, float* __restrict__ mh,
                  u16* As, float* muS, int bid, int tid) {
  constexpr int QT = 64, KCH = C / 8;
  int wave = tid >> 6, lane = tid & 63;
  int row0 = bid * QT;

  for (int i = tid; i < C; i += 256) muS[i] = mu[i];
  __syncthreads();
  for (int u = tid; u < QT * KCH; u += 256) {
    int r = u / KCH, cc = u % KCH;
    bf8v v = *(const bf8v*)(qfb + (size_t)(row0 + r) * C + cc * 8);
    s8v d;
#pragma unroll
    for (int i = 0; i < 8; ++i) d[i] = (short)f2bf((float)v[i] - muS[cc * 8 + i]);
    *(s8v*)(As + r * C + ((cc ^ (r & 7)) << 3)) = d;
  }
  __syncthreads();

  int arow = wave * 16 + (lane & 15);
  int kb = lane >> 4;
  float mm[4] = {0.f, 0.f, 0.f, 0.f};
#pragma unroll
  for (int cb = 0; cb < C / 16; ++cb) {
    f4v acc = (f4v){0.f, 0.f, 0.f, 0.f};
    int bcol = cb * 16 + (lane & 15);
#pragma unroll
    for (int kk = 0; kk < C / 32; ++kk) {
      int kc = kk * 4 + kb;
      bf8v a = *(const bf8v*)(As + arow * C + ((kc ^ (arow & 7)) << 3));
      bf8v b = *(const bf8v*)(icovb + (size_t)bcol * C + kc * 8);
      acc = __builtin_amdgcn_mfma_f32_16x16x32_bf16(a, b, acc, 0, 0, 0);
    }
#pragma unroll
    for (int r = 0; r < 4; ++r) {
      int row = wave * 16 + (lane >> 4) * 4 + r;
      int col = cb * 16 + (lane & 15);
      float dv = bf2f(As[row * C + (((col >> 3) ^ (row & 7)) << 3) + (col & 7)]);
      mm[r] += acc[r] * dv;
    }
  }
#pragma unroll
  for (int r = 0; r < 4; ++r) {
    float v = mm[r];
    v += __shfl_xor(v, 1); v += __shfl_xor(v, 2);
    v += __shfl_xor(v, 4); v += __shfl_xor(v, 8);
    if ((lane & 15) == 0)
      mh[row0 + wave * 16 + (lane >> 4) * 4 + r] = sqrtf(fmaxf(v, EPSF));
  }
}

// fused launcher: bid<784: score (even->C=256, odd->C=128); bid>=784: maha
// (maha depends only on k_prep outputs -> safe to co-dispatch; backfills idle CUs)
__global__ __launch_bounds__(256, 2) void k_score_f(
    const u16* __restrict__ qf3, const u16* __restrict__ m3t,
    const float* __restrict__ mn3, float* __restrict__ kp3, float* __restrict__ qn3,
    const u16* __restrict__ qf2, const u16* __restrict__ m2t,
    const float* __restrict__ mn2, float* __restrict__ kp2, float* __restrict__ qn2,
    const float* __restrict__ mean2, const float* __restrict__ mean3,
    const u16* __restrict__ ic2b, const u16* __restrict__ ic3b,
    float* __restrict__ mh2, float* __restrict__ mh3) {
  __shared__ alignas(16) u16 Bs[3 * 8192];      // 48KB; maha aliases: As(32KB)+muS(1KB)
  __shared__ alignas(16) float mnS[3 * 64];
  int bid = blockIdx.x, tid = threadIdx.x;
  if (bid < 784) {
    if (bid & 1) score_body<128, 8>(qf2, m2t, mn2, kp2, qn2, bid >> 1, Bs, mnS, tid);
    else         score_body<256, 8>(qf3, m3t, mn3, kp3, qn3, bid >> 1, Bs, mnS, tid);
  } else {
    int b2 = bid - 784;
    u16* As = Bs;
    float* muS = (float*)(Bs + 16384);          // after the 32KB As region
    if (b2 < 196) maha_dev<128>(qf2, mean2, ic2b, mh2, As, muS, b2, tid);
    else          maha_dev<256>(qf3, mean3, ic3b, mh3, As, muS, b2 - 196, tid);
  }
}

// ================= combine: merge knn splits (+qn), build maps =================
template<int S>
DEV float knn_merge(const float* kp, int n, float qv) {
  float t0 = 1e30f, t1 = 1e30f, t2 = 1e30f, t3 = 1e30f, t4 = 1e30f;
  const float* p = kp + (size_t)n * S * 5;
#pragma unroll
  for (int i = 0; i < S * 5; ++i) ins5(p[i], t0, t1, t2, t3, t4);
  return 0.2f * (sqrtf(fmaxf(t0 + qv, EPSF)) + sqrtf(fmaxf(t1 + qv, EPSF)) +
                 sqrtf(fmaxf(t2 + qv, EPSF)) + sqrtf(fmaxf(t3 + qv, EPSF)) +
                 sqrtf(fmaxf(t4 + qv, EPSF)));
}

__global__ __launch_bounds__(256) void k_combine(
    const float* __restrict__ kp2, const float* __restrict__ kp3,
    const float* __restrict__ qn2, const float* __restrict__ qn3,
    const float* __restrict__ mh2, const float* __restrict__ mh3,
    float* __restrict__ out) {
  int n = blockIdx.x * 256 + threadIdx.x;
  float m2v = 0.5f * (knn_merge<8>(kp2, n, qn2[n]) + mh2[n]);
  float m3v = 0.5f * (knn_merge<8>(kp3, n, qn3[n]) + mh3[n]);
  out[16 + n] = 0.5f * (m2v + m3v);
  out[16 + NQ + n] = m2v;
  out[16 + 2 * NQ + n] = m3v;
}

// ================= per-image top-10 mean over 784-pixel map =================
__global__ __launch_bounds__(256) void k_top10(const float* __restrict__ comb, float* __restrict__ pred) {
  __shared__ float vals[1024];
  __shared__ float rv[256];
  __shared__ int ri[256];
  __shared__ float ssum;
  int b = blockIdx.x, tid = threadIdx.x;
  for (int i = tid; i < 1024; i += 256) vals[i] = (i < PP) ? comb[b * PP + i] : -1e30f;
  if (tid == 0) ssum = 0.f;
  __syncthreads();
  for (int it = 0; it < 10; ++it) {
    float bv = -1e30f; int bi = 0;
    for (int i = tid; i < 1024; i += 256) { float v = vals[i]; if (v > bv) { bv = v; bi = i; } }
    rv[tid] = bv; ri[tid] = bi;
    __syncthreads();
    for (int s = 128; s; s >>= 1) {
      if (tid < s && rv[tid + s] > rv[tid]) { rv[tid] = rv[tid + s]; ri[tid] = ri[tid + s]; }
      __syncthreads();
    }
    if (tid == 0) { ssum += rv[0]; vals[ri[0]] = -1e30f; }
    __syncthreads();
  }
  if (tid == 0) pred[b] = ssum * 0.1f;
}

extern "C" void kernel_launch(void* const* d_in, const int* in_sizes, int n_in,
                              void* d_out, int out_size, void* d_ws, size_t ws_size,
                              hipStream_t stream) {
  const float* q2    = (const float*)d_in[0];
  const float* q3    = (const float*)d_in[1];
  const float* mem2  = (const float*)d_in[2];
  const float* mem3  = (const float*)d_in[3];
  const float* mean2 = (const float*)d_in[4];
  const float* mean3 = (const float*)d_in[5];
  const float* icov2 = (const float*)d_in[6];
  const float* icov3 = (const float*)d_in[7];
  float* out = (float*)d_out;

  char* w = (char*)d_ws;
  auto alloc = [&](size_t bytes) { void* p = (void*)w; w += (bytes + 255) & ~(size_t)255; return p; };
  u16* qf2b = (u16*)alloc((size_t)NQ * 128 * 2);
  u16* qf3b = (u16*)alloc((size_t)NQ * 256 * 2);
  u16* m2t  = (u16*)alloc((size_t)MM * 128 * 2);
  u16* m3t  = (u16*)alloc((size_t)MM * 256 * 2);
  u16* ic2b = (u16*)alloc((size_t)128 * 128 * 2);
  u16* ic3b = (u16*)alloc((size_t)256 * 256 * 2);
  float* qn2 = (float*)alloc((size_t)NQ * 4);
  float* qn3 = (float*)alloc((size_t)NQ * 4);
  float* mn2 = (float*)alloc((size_t)MM * 4);
  float* mn3 = (float*)alloc((size_t)MM * 4);
  float* kp2 = (float*)alloc((size_t)NQ * 8 * 5 * 4);
  float* kp3 = (float*)alloc((size_t)NQ * 8 * 5 * 4);
  float* mh2 = (float*)alloc((size_t)NQ * 4);
  float* mh3 = (float*)alloc((size_t)NQ * 4);

  k_prep<<<6488, 256, 0, stream>>>(q2, q3, mem2, mem3, icov2, icov3,
                                   qf2b, qf3b, m2t, m3t, ic2b, ic3b, mn2, mn3);

  // fused score (+q-norms) + co-dispatched maha: 784 score blocks + 392 maha blocks
  k_score_f<<<1176, 256, 0, stream>>>(qf3b, m3t, mn3, kp3, qn3,
                                      qf2b, m2t, mn2, kp2, qn2,
                                      mean2, mean3, ic2b, ic3b, mh2, mh3);

  k_combine<<<NQ / 256, 256, 0, stream>>>(kp2, kp3, qn2, qn3, mh2, mh3, out);
  k_top10<<<16, 256, 0, stream>>>(out + 16, out);

  (void)in_sizes; (void)n_in; (void)out_size; (void)ws_size;
}

// Round 17
// 173.013 us; speedup vs baseline: 1.6019x; 1.0545x over previous
//
#include <hip/hip_runtime.h>

typedef unsigned short u16;
typedef unsigned int u32;
typedef __attribute__((ext_vector_type(8))) __bf16 bf8v;    // MFMA A/B operand (8 bf16)
typedef __attribute__((ext_vector_type(8))) short s8v;      // same bits, for packing
typedef __attribute__((ext_vector_type(4))) float f4v;
typedef __attribute__((ext_vector_type(16))) float f16v;    // 32x32 MFMA C/D

#define DEV static __device__ __forceinline__

constexpr int NQ = 12544;   // B*H*W = 16*28*28
constexpr int MM = 8192;    // memory bank rows
constexpr int PP = 784;     // H*W
constexpr float EPSF = 1e-12f;

DEV u16 f2bf(float f) {  // RNE f32 -> bf16 (inputs are finite normals)
  u32 u = __float_as_uint(f);
  return (u16)((u + 0x7FFFu + ((u >> 16) & 1u)) >> 16);
}
DEV float bf2f(u16 h) { return __uint_as_float((u32)h << 16); }

DEV void gl2lds16(const u16* g, u16* l) {
  __builtin_amdgcn_global_load_lds(
      (const __attribute__((address_space(1))) unsigned int*)(g),
      (__attribute__((address_space(3))) unsigned int*)(l), 16, 0, 0);
}
DEV void gl2lds4(const float* g, float* l) {
  __builtin_amdgcn_global_load_lds(
      (const __attribute__((address_space(1))) unsigned int*)(g),
      (__attribute__((address_space(3))) unsigned int*)(l), 4, 0, 0);
}

template<int N> DEV void wait_vm() {   // counted vmcnt (T4): literal immediates only
  if constexpr (N == 0) asm volatile("s_waitcnt vmcnt(0)" ::: "memory");
  else if constexpr (N == 3) asm volatile("s_waitcnt vmcnt(3)" ::: "memory");
  else if constexpr (N == 5) asm volatile("s_waitcnt vmcnt(5)" ::: "memory");
  else static_assert(N == 0, "unsupported vmcnt");
}

// branchless sorted insert: keep 5 smallest in a0<=..<=a4
DEV void ins5(float v, float& a0, float& a1, float& a2, float& a3, float& a4) {
  float hi;
  hi = fmaxf(v, a0); a0 = fminf(v, a0); v = hi;
  hi = fmaxf(v, a1); a1 = fminf(v, a1); v = hi;
  hi = fmaxf(v, a2); a2 = fminf(v, a2); v = hi;
  hi = fmaxf(v, a3); a3 = fminf(v, a3); v = hi;
  a4 = fminf(v, a4);
}

// ================= fused prep =================
DEV void pack_bf16_dev(const float* __restrict__ x, u16* __restrict__ y, int bid, int tid) {
  int g = bid * 256 + tid;
  const float4* px = (const float4*)x + (size_t)g * 2;
  float4 a = px[0], b = px[1];
  s8v o;
  o[0] = (short)f2bf(a.x); o[1] = (short)f2bf(a.y); o[2] = (short)f2bf(a.z); o[3] = (short)f2bf(a.w);
  o[4] = (short)f2bf(b.x); o[5] = (short)f2bf(b.y); o[6] = (short)f2bf(b.z); o[7] = (short)f2bf(b.w);
  ((s8v*)y)[g] = o;
}

// mem pack: store -2*m (exact bf16 scale) K-MAJOR in global: yT[chunk][row][8]
template<int C>
DEV void pack_mem_dev(const float* __restrict__ x, u16* __restrict__ yT, float* __restrict__ nrm,
                      int bid, int tid) {
  int row = bid * 4 + (tid >> 6), lane = tid & 63;
  constexpr int E = C / 64;
  const float* src = x + (size_t)row * C + lane * E;
  float s = 0.f;
  if constexpr (E == 4) {
    float4 v = *(const float4*)src;
    s = v.x * v.x + v.y * v.y + v.z * v.z + v.w * v.w;
    u32 lo = (u32)f2bf(-2.f * v.x) | ((u32)f2bf(-2.f * v.y) << 16);
    u32 hi = (u32)f2bf(-2.f * v.z) | ((u32)f2bf(-2.f * v.w) << 16);
    size_t di = ((size_t)(lane >> 1) * MM + row) * 8 + (lane & 1) * 4;
    *(uint2*)(yT + di) = make_uint2(lo, hi);
  } else {
    float2 v = *(const float2*)src;
    s = v.x * v.x + v.y * v.y;
    size_t di = ((size_t)(lane >> 2) * MM + row) * 8 + (lane & 3) * 2;
    *(u32*)(yT + di) = (u32)f2bf(-2.f * v.x) | ((u32)f2bf(-2.f * v.y) << 16);
  }
#pragma unroll
  for (int m = 1; m < 64; m <<= 1) s += __shfl_xor(s, m);
  if (lane == 0) nrm[row] = s;
}

template<int C>
DEV void pack_q_dev(const float* __restrict__ q, u16* __restrict__ qfb, int bid, int tid) {
  int g = bid * 256 + tid;
  int n = g % NQ;
  int cc = g / NQ;
  int b = n / PP, p = n % PP;
  int c0 = cc * 8;
  const float* src = q + ((size_t)b * C + c0) * PP + p;
  s8v o;
#pragma unroll
  for (int i = 0; i < 8; ++i) o[i] = (short)f2bf(src[(size_t)i * PP]);
  ((s8v*)qfb)[((size_t)n * C + c0) >> 3] = o;
}

__global__ __launch_bounds__(256) void k_prep(
    const float* __restrict__ q2, const float* __restrict__ q3,
    const float* __restrict__ mem2, const float* __restrict__ mem3,
    const float* __restrict__ icov2, const float* __restrict__ icov3,
    u16* __restrict__ qf2b, u16* __restrict__ qf3b,
    u16* __restrict__ m2t, u16* __restrict__ m3t,
    u16* __restrict__ ic2b, u16* __restrict__ ic3b,
    float* __restrict__ mn2, float* __restrict__ mn3) {
  int bid = blockIdx.x, tid = threadIdx.x;
  if (bid < 2048)       pack_mem_dev<128>(mem2, m2t, mn2, bid, tid);
  else if (bid < 4096)  pack_mem_dev<256>(mem3, m3t, mn3, bid - 2048, tid);
  else if (bid < 4104)  pack_bf16_dev(icov2, ic2b, bid - 4096, tid);
  else if (bid < 4136)  pack_bf16_dev(icov3, ic3b, bid - 4104, tid);
  else if (bid < 4920)  pack_q_dev<128>(q2, qf2b, bid - 4136, tid);
  else                  pack_q_dev<256>(q3, qf3b, bid - 4920, tid);
}

// ================= fused distances + per-row 5 smallest d2' =================
// R16 body + (a) 2-buffer pipeline (33KB LDS -> 4 blocks/CU co-resident) and
// (b) sort8 + positional-merge scan: after sorting 8 candidates, s_k has k
// elements below it -> inserts from position k; s5..s7 can NEVER enter top-5.
// 67 VALU / 8 candidates vs 88 guarded before; guards deleted (wave-level
// any-lane probability ~1 made them pure overhead).
template<int C, int NSPLIT>
DEV void score_body(const u16* __restrict__ qf, const u16* __restrict__ memT,
                    const float* __restrict__ mn, float* __restrict__ kp,
                    float* __restrict__ qn,
                    int bid2, u16* __restrict__ BsB, float* __restrict__ mnSB, int tid) {
  constexpr int MT = 32, MS = MM / NSPLIT, NT = MS / MT;   // NT = 32
  constexpr int CHUNKS = C / 8;           // 16B chunks per mem row (32 / 16)
  constexpr int PAIRS = CHUNKS / 2;       // K-groups of 16 elems (16 / 8)
  constexpr int SIT = PAIRS / 4;          // gl2lds16 per wave per tile (4 / 2)
  constexpr int P = SIT + 1;              // + mn load (5 / 3)
  constexpr int BSTRIDE = 8192;           // u16 per LDS buffer (16KB, sized for C=256)
  constexpr int QROWS = 4 * 64;           // 4 waves x 64 q-cols = 256
  constexpr int RT = NQ / QROWS;          // 49 exactly
  static_assert(NT >= 3, "pipeline needs NT>=3");

  const int wave = tid >> 6, lane = tid & 63;
  const int l31 = lane & 31, kh = lane >> 5;
  const int rt = bid2 % RT, split = bid2 / RT;
  const int row0 = rt * QROWS, mb0 = split * MS;

  // q fragments (B operand; loop-invariant) -> registers, pinned. 2 col-groups.
  bf8v qv[2][PAIRS];
#pragma unroll
  for (int cg = 0; cg < 2; ++cg)
#pragma unroll
    for (int kk = 0; kk < PAIRS; ++kk)
      qv[cg][kk] = *(const bf8v*)(qf + (size_t)(row0 + wave * 64 + cg * 32 + l31) * C + kk * 16 + kh * 8);
#pragma unroll
  for (int cg = 0; cg < 2; ++cg)
#pragma unroll
    for (int kk = 0; kk < PAIRS; ++kk)
      asm volatile("" : "+v"(qv[cg][kk]));

  // free q-norm: lane holds K-half kh of q-rows (row0+wave*64+cg*32+l31)
  if (split == 0) {
#pragma unroll
    for (int cg = 0; cg < 2; ++cg) {
      float s = 0.f;
#pragma unroll
      for (int kk = 0; kk < PAIRS; ++kk)
#pragma unroll
        for (int i = 0; i < 8; ++i) { float v = (float)qv[cg][kk][i]; s = fmaf(v, v, s); }
      s += __shfl_xor(s, 32);
      if (lane < 32) qn[row0 + wave * 64 + cg * 32 + l31] = s;
    }
  }

  auto STAGE = [&](int buf, int t) {   // exactly P vmem ops per wave
    const int mrow0 = mb0 + t * MT;
    u16* Bs = BsB + buf * BSTRIDE;
#pragma unroll
    for (int it = 0; it < SIT; ++it) {
      int cp2 = wave + it * 4;
      gl2lds16(memT + ((size_t)(cp2 * 2 + kh) * MM + mrow0 + l31) * 8,
               Bs + cp2 * 512 + lane * 8);
    }
    gl2lds4(mn + mrow0 + (lane & 31), mnSB + buf * 64 + (lane & 31));   // dup: benign
  };

  float t0 = 1e30f, t1 = 1e30f, t2 = 1e30f, t3 = 1e30f, t4 = 1e30f;   // cg=0
  float u0 = 1e30f, u1 = 1e30f, u2 = 1e30f, u3 = 1e30f, u4 = 1e30f;   // cg=1

  auto CE = [](float& a, float& b) { float lo = fminf(a, b), hi = fmaxf(a, b); a = lo; b = hi; };

  // sort 8 candidates (19-CE Batcher network), then positional merge into a0..a4
  auto scan8 = [&](float x0, float x1, float x2, float x3,
                   float x4, float x5, float x6, float x7,
                   float& a0, float& a1, float& a2, float& a3, float& a4) {
    CE(x0, x1); CE(x2, x3); CE(x4, x5); CE(x6, x7);
    CE(x0, x2); CE(x1, x3); CE(x4, x6); CE(x5, x7);
    CE(x1, x2); CE(x5, x6); CE(x0, x4); CE(x3, x7);
    CE(x1, x5); CE(x2, x6);
    CE(x1, x4); CE(x3, x6);
    CE(x2, x4); CE(x3, x5);
    CE(x3, x4);
    // x0<=x1<=...<=x7 ; x5..x7 have >=5 elements below -> dropped
    ins5(x0, a0, a1, a2, a3, a4);                         // 10
    float v, hi;
    v = x1;                                               // from pos 1 (8)
    hi = fmaxf(v, a1); a1 = fminf(v, a1); v = hi;
    hi = fmaxf(v, a2); a2 = fminf(v, a2); v = hi;
    hi = fmaxf(v, a3); a3 = fminf(v, a3); v = hi;
    a4 = fminf(v, a4);
    v = x2;                                               // from pos 2 (6)
    hi = fmaxf(v, a2); a2 = fminf(v, a2); v = hi;
    hi = fmaxf(v, a3); a3 = fminf(v, a3); v = hi;
    a4 = fminf(v, a4);
    v = x3;                                               // from pos 3 (4)
    hi = fmaxf(v, a3); a3 = fminf(v, a3); v = hi;
    a4 = fminf(v, a4);
    a4 = fminf(a4, x4);                                   // pos 4 (1)
  };

  auto COMPUTE = [&](int cur) {
    f16v acc[2];
#pragma unroll
    for (int g = 0; g < 4; ++g) {
      f4v m4 = *(const f4v*)(mnSB + cur * 64 + g * 8 + kh * 4);
#pragma unroll
      for (int cg = 0; cg < 2; ++cg) {
        acc[cg][4 * g + 0] = m4[0]; acc[cg][4 * g + 1] = m4[1];
        acc[cg][4 * g + 2] = m4[2]; acc[cg][4 * g + 3] = m4[3];
      }
    }
    const u16* Bb = BsB + cur * BSTRIDE + l31 * 8 + kh * 256;
#pragma unroll
    for (int kk = 0; kk < PAIRS; ++kk) {
      bf8v mf = *(const bf8v*)(Bb + kk * 512);
      acc[0] = __builtin_amdgcn_mfma_f32_32x32x16_bf16(mf, qv[0][kk], acc[0], 0, 0, 0);
      acc[1] = __builtin_amdgcn_mfma_f32_32x32x16_bf16(mf, qv[1][kk], acc[1], 0, 0, 0);
    }
    scan8(acc[0][0], acc[0][1], acc[0][2], acc[0][3], acc[0][4], acc[0][5], acc[0][6], acc[0][7],
          t0, t1, t2, t3, t4);
    scan8(acc[0][8], acc[0][9], acc[0][10], acc[0][11], acc[0][12], acc[0][13], acc[0][14], acc[0][15],
          t0, t1, t2, t3, t4);
    scan8(acc[1][0], acc[1][1], acc[1][2], acc[1][3], acc[1][4], acc[1][5], acc[1][6], acc[1][7],
          u0, u1, u2, u3, u4);
    scan8(acc[1][8], acc[1][9], acc[1][10], acc[1][11], acc[1][12], acc[1][13], acc[1][14], acc[1][15],
          u0, u1, u2, u3, u4);
  };

  STAGE(0, 0); STAGE(1, 1);   // 2 tiles in flight (2P outstanding)

  for (int t = 0; t < NT - 2; ++t) {
    const int cur = t & 1;
    wait_vm<P>();                       // tile t landed; t+1 still flying
    __builtin_amdgcn_sched_barrier(0);
    __builtin_amdgcn_s_barrier();
    __builtin_amdgcn_sched_barrier(0);
    COMPUTE(cur);
    __builtin_amdgcn_sched_barrier(0);
    __builtin_amdgcn_s_barrier();       // all waves done reading Bs[cur]
    __builtin_amdgcn_sched_barrier(0);
    STAGE(cur, t + 2);                  // refill freed buffer
  }
  {
    wait_vm<P>();
    __builtin_amdgcn_sched_barrier(0);
    __builtin_amdgcn_s_barrier();
    __builtin_amdgcn_sched_barrier(0);
    COMPUTE((NT - 2) & 1);
    __builtin_amdgcn_sched_barrier(0);
    __builtin_amdgcn_s_barrier();
    wait_vm<0>();
    __builtin_amdgcn_sched_barrier(0);
    __builtin_amdgcn_s_barrier();
    __builtin_amdgcn_sched_barrier(0);
    COMPUTE((NT - 1) & 1);
  }

  // per cg: merge the 2 lanes holding the same q-col (lane, lane+32), write
  {
    float r0 = __shfl_xor(t0, 32), r1 = __shfl_xor(t1, 32), r2 = __shfl_xor(t2, 32),
          r3 = __shfl_xor(t3, 32), r4 = __shfl_xor(t4, 32);
    ins5(r0, t0, t1, t2, t3, t4);
    ins5(r1, t0, t1, t2, t3, t4);
    ins5(r2, t0, t1, t2, t3, t4);
    ins5(r3, t0, t1, t2, t3, t4);
    ins5(r4, t0, t1, t2, t3, t4);
    r0 = __shfl_xor(u0, 32); r1 = __shfl_xor(u1, 32); r2 = __shfl_xor(u2, 32);
    r3 = __shfl_xor(u3, 32); r4 = __shfl_xor(u4, 32);
    ins5(r0, u0, u1, u2, u3, u4);
    ins5(r1, u0, u1, u2, u3, u4);
    ins5(r2, u0, u1, u2, u3, u4);
    ins5(r3, u0, u1, u2, u3, u4);
    ins5(r4, u0, u1, u2, u3, u4);
  }
  if (lane < 32) {
    int g0 = row0 + wave * 64 + l31;
    float* o = kp + ((size_t)g0 * NSPLIT + split) * 5;
    o[0] = t0; o[1] = t1; o[2] = t2; o[3] = t3; o[4] = t4;
    float* o1 = kp + ((size_t)(g0 + 32) * NSPLIT + split) * 5;
    o1[0] = u0; o1[1] = u1; o1[2] = u2; o1[3] = u3; o1[4] = u4;
  }
}

// ================= Mahalanobis body (co-dispatched with score) =================
template<int C>
DEV void maha_dev(const u16* __restrict__ qfb, const float* __restrict__ mu,
                  const u16* __restrict__ icovb, float* __restrict__ mh,
                  u16* As, float* muS, int bid, int tid) {
  constexpr int QT = 64, KCH = C / 8;
  int wave = tid >> 6, lane = tid & 63;
  int row0 = bid * QT;

  for (int i = tid; i < C; i += 256) muS[i] = mu[i];
  __syncthreads();
  for (int u = tid; u < QT * KCH; u += 256) {
    int r = u / KCH, cc = u % KCH;
    bf8v v = *(const bf8v*)(qfb + (size_t)(row0 + r) * C + cc * 8);
    s8v d;
#pragma unroll
    for (int i = 0; i < 8; ++i) d[i] = (short)f2bf((float)v[i] - muS[cc * 8 + i]);
    *(s8v*)(As + r * C + ((cc ^ (r & 7)) << 3)) = d;
  }
  __syncthreads();

  int arow = wave * 16 + (lane & 15);
  int kb = lane >> 4;
  float mm[4] = {0.f, 0.f, 0.f, 0.f};
#pragma unroll
  for (int cb = 0; cb < C / 16; ++cb) {
    f4v acc = (f4v){0.f, 0.f, 0.f, 0.f};
    int bcol = cb * 16 + (lane & 15);
#pragma unroll
    for (int kk = 0; kk < C / 32; ++kk) {
      int kc = kk * 4 + kb;
      bf8v a = *(const bf8v*)(As + arow * C + ((kc ^ (arow & 7)) << 3));
      bf8v b = *(const bf8v*)(icovb + (size_t)bcol * C + kc * 8);
      acc = __builtin_amdgcn_mfma_f32_16x16x32_bf16(a, b, acc, 0, 0, 0);
    }
#pragma unroll
    for (int r = 0; r < 4; ++r) {
      int row = wave * 16 + (lane >> 4) * 4 + r;
      int col = cb * 16 + (lane & 15);
      float dv = bf2f(As[row * C + (((col >> 3) ^ (row & 7)) << 3) + (col & 7)]);
      mm[r] += acc[r] * dv;
    }
  }
#pragma unroll
  for (int r = 0; r < 4; ++r) {
    float v = mm[r];
    v += __shfl_xor(v, 1); v += __shfl_xor(v, 2);
    v += __shfl_xor(v, 4); v += __shfl_xor(v, 8);
    if ((lane & 15) == 0)
      mh[row0 + wave * 16 + (lane >> 4) * 4 + r] = sqrtf(fmaxf(v, EPSF));
  }
}

// fused launcher: bid<784: score (even->C=256, odd->C=128); bid>=784: maha
__global__ __launch_bounds__(256, 2) void k_score_f(
    const u16* __restrict__ qf3, const u16* __restrict__ m3t,
    const float* __restrict__ mn3, float* __restrict__ kp3, float* __restrict__ qn3,
    const u16* __restrict__ qf2, const u16* __restrict__ m2t,
    const float* __restrict__ mn2, float* __restrict__ kp2, float* __restrict__ qn2,
    const float* __restrict__ mean2, const float* __restrict__ mean3,
    const u16* __restrict__ ic2b, const u16* __restrict__ ic3b,
    float* __restrict__ mh2, float* __restrict__ mh3) {
  __shared__ alignas(16) u16 Bs[2 * 8192];      // 32KB (score dbuf; maha As aliases all of it)
  __shared__ alignas(16) float mnS[2 * 64];
  __shared__ alignas(16) float muX[256];        // maha mu scratch
  int bid = blockIdx.x, tid = threadIdx.x;
  if (bid < 784) {
    if (bid & 1) score_body<128, 8>(qf2, m2t, mn2, kp2, qn2, bid >> 1, Bs, mnS, tid);
    else         score_body<256, 8>(qf3, m3t, mn3, kp3, qn3, bid >> 1, Bs, mnS, tid);
  } else {
    int b2 = bid - 784;
    if (b2 < 196) maha_dev<128>(qf2, mean2, ic2b, mh2, Bs, muX, b2, tid);
    else          maha_dev<256>(qf3, mean3, ic3b, mh3, Bs, muX, b2 - 196, tid);
  }
}

// ================= combine: merge knn splits (+qn), build maps =================
template<int S>
DEV float knn_merge(const float* kp, int n, float qv) {
  float t0 = 1e30f, t1 = 1e30f, t2 = 1e30f, t3 = 1e30f, t4 = 1e30f;
  const float* p = kp + (size_t)n * S * 5;
#pragma unroll
  for (int i = 0; i < S * 5; ++i) ins5(p[i], t0, t1, t2, t3, t4);
  return 0.2f * (sqrtf(fmaxf(t0 + qv, EPSF)) + sqrtf(fmaxf(t1 + qv, EPSF)) +
                 sqrtf(fmaxf(t2 + qv, EPSF)) + sqrtf(fmaxf(t3 + qv, EPSF)) +
                 sqrtf(fmaxf(t4 + qv, EPSF)));
}

__global__ __launch_bounds__(256) void k_combine(
    const float* __restrict__ kp2, const float* __restrict__ kp3,
    const float* __restrict__ qn2, const float* __restrict__ qn3,
    const float* __restrict__ mh2, const float* __restrict__ mh3,
    float* __restrict__ out) {
  int n = blockIdx.x * 256 + threadIdx.x;
  float m2v = 0.5f * (knn_merge<8>(kp2, n, qn2[n]) + mh2[n]);
  float m3v = 0.5f * (knn_merge<8>(kp3, n, qn3[n]) + mh3[n]);
  out[16 + n] = 0.5f * (m2v + m3v);
  out[16 + NQ + n] = m2v;
  out[16 + 2 * NQ + n] = m3v;
}

// ================= per-image top-10 mean over 784-pixel map =================
__global__ __launch_bounds__(256) void k_top10(const float* __restrict__ comb, float* __restrict__ pred) {
  __shared__ float vals[1024];
  __shared__ float rv[256];
  __shared__ int ri[256];
  __shared__ float ssum;
  int b = blockIdx.x, tid = threadIdx.x;
  for (int i = tid; i < 1024; i += 256) vals[i] = (i < PP) ? comb[b * PP + i] : -1e30f;
  if (tid == 0) ssum = 0.f;
  __syncthreads();
  for (int it = 0; it < 10; ++it) {
    float bv = -1e30f; int bi = 0;
    for (int i = tid; i < 1024; i += 256) { float v = vals[i]; if (v > bv) { bv = v; bi = i; } }
    rv[tid] = bv; ri[tid] = bi;
    __syncthreads();
    for (int s = 128; s; s >>= 1) {
      if (tid < s && rv[tid + s] > rv[tid]) { rv[tid] = rv[tid + s]; ri[tid] = ri[tid + s]; }
      __syncthreads();
    }
    if (tid == 0) { ssum += rv[0]; vals[ri[0]] = -1e30f; }
    __syncthreads();
  }
  if (tid == 0) pred[b] = ssum * 0.1f;
}

extern "C" void kernel_launch(void* const* d_in, const int* in_sizes, int n_in,
                              void* d_out, int out_size, void* d_ws, size_t ws_size,
                              hipStream_t stream) {
  const float* q2    = (const float*)d_in[0];
  const float* q3    = (const float*)d_in[1];
  const float* mem2  = (const float*)d_in[2];
  const float* mem3  = (const float*)d_in[3];
  const float* mean2 = (const float*)d_in[4];
  const float* mean3 = (const float*)d_in[5];
  const float* icov2 = (const float*)d_in[6];
  const float* icov3 = (const float*)d_in[7];
  float* out = (float*)d_out;

  char* w = (char*)d_ws;
  auto alloc = [&](size_t bytes) { void* p = (void*)w; w += (bytes + 255) & ~(size_t)255; return p; };
  u16* qf2b = (u16*)alloc((size_t)NQ * 128 * 2);
  u16* qf3b = (u16*)alloc((size_t)NQ * 256 * 2);
  u16* m2t  = (u16*)alloc((size_t)MM * 128 * 2);
  u16* m3t  = (u16*)alloc((size_t)MM * 256 * 2);
  u16* ic2b = (u16*)alloc((size_t)128 * 128 * 2);
  u16* ic3b = (u16*)alloc((size_t)256 * 256 * 2);
  float* qn2 = (float*)alloc((size_t)NQ * 4);
  float* qn3 = (float*)alloc((size_t)NQ * 4);
  float* mn2 = (float*)alloc((size_t)MM * 4);
  float* mn3 = (float*)alloc((size_t)MM * 4);
  float* kp2 = (float*)alloc((size_t)NQ * 8 * 5 * 4);
  float* kp3 = (float*)alloc((size_t)NQ * 8 * 5 * 4);
  float* mh2 = (float*)alloc((size_t)NQ * 4);
  float* mh3 = (float*)alloc((size_t)NQ * 4);

  k_prep<<<6488, 256, 0, stream>>>(q2, q3, mem2, mem3, icov2, icov3,
                                   qf2b, qf3b, m2t, m3t, ic2b, ic3b, mn2, mn3);

  // fused score (+q-norms) + co-dispatched maha: 784 score blocks + 392 maha blocks
  k_score_f<<<1176, 256, 0, stream>>>(qf3b, m3t, mn3, kp3, qn3,
                                      qf2b, m2t, mn2, kp2, qn2,
                                      mean2, mean3, ic2b, ic3b, mh2, mh3);

  k_combine<<<NQ / 256, 256, 0, stream>>>(kp2, kp3, qn2, qn3, mh2, mh3, out);
  k_top10<<<16, 256, 0, stream>>>(out + 16, out);

  (void)in_sizes; (void)n_in; (void)out_size; (void)ws_size;
}

// Round 18
// 168.939 us; speedup vs baseline: 1.6405x; 1.0241x over previous
//
#include <hip/hip_runtime.h>

typedef unsigned short u16;
typedef unsigned int u32;
typedef __attribute__((ext_vector_type(8))) __bf16 bf8v;    // MFMA A/B operand (8 bf16)
typedef __attribute__((ext_vector_type(8))) short s8v;      // same bits, for packing
typedef __attribute__((ext_vector_type(4))) float f4v;
typedef __attribute__((ext_vector_type(16))) float f16v;    // 32x32 MFMA C/D

#define DEV static __device__ __forceinline__

constexpr int NQ = 12544;   // B*H*W = 16*28*28
constexpr int MM = 8192;    // memory bank rows
constexpr int PP = 784;     // H*W
constexpr float EPSF = 1e-12f;

DEV u16 f2bf(float f) {  // RNE f32 -> bf16 (inputs are finite normals)
  u32 u = __float_as_uint(f);
  return (u16)((u + 0x7FFFu + ((u >> 16) & 1u)) >> 16);
}
DEV float bf2f(u16 h) { return __uint_as_float((u32)h << 16); }

DEV void gl2lds16(const u16* g, u16* l) {
  __builtin_amdgcn_global_load_lds(
      (const __attribute__((address_space(1))) unsigned int*)(g),
      (__attribute__((address_space(3))) unsigned int*)(l), 16, 0, 0);
}
DEV void gl2lds4(const float* g, float* l) {
  __builtin_amdgcn_global_load_lds(
      (const __attribute__((address_space(1))) unsigned int*)(g),
      (__attribute__((address_space(3))) unsigned int*)(l), 4, 0, 0);
}

template<int N> DEV void wait_vm() {   // counted vmcnt (T4): literal immediates only
  if constexpr (N == 0) asm volatile("s_waitcnt vmcnt(0)" ::: "memory");
  else if constexpr (N == 5) asm volatile("s_waitcnt vmcnt(5)" ::: "memory");
  else if constexpr (N == 9) asm volatile("s_waitcnt vmcnt(9)" ::: "memory");
  else static_assert(N == 0, "unsupported vmcnt");
}

// branchless sorted insert: keep 5 smallest in a0<=..<=a4
DEV void ins5(float v, float& a0, float& a1, float& a2, float& a3, float& a4) {
  float hi;
  hi = fmaxf(v, a0); a0 = fminf(v, a0); v = hi;
  hi = fmaxf(v, a1); a1 = fminf(v, a1); v = hi;
  hi = fmaxf(v, a2); a2 = fminf(v, a2); v = hi;
  hi = fmaxf(v, a3); a3 = fminf(v, a3); v = hi;
  a4 = fminf(v, a4);
}

// ================= fused prep =================
DEV void pack_bf16_dev(const float* __restrict__ x, u16* __restrict__ y, int bid, int tid) {
  int g = bid * 256 + tid;
  const float4* px = (const float4*)x + (size_t)g * 2;
  float4 a = px[0], b = px[1];
  s8v o;
  o[0] = (short)f2bf(a.x); o[1] = (short)f2bf(a.y); o[2] = (short)f2bf(a.z); o[3] = (short)f2bf(a.w);
  o[4] = (short)f2bf(b.x); o[5] = (short)f2bf(b.y); o[6] = (short)f2bf(b.z); o[7] = (short)f2bf(b.w);
  ((s8v*)y)[g] = o;
}

// mem pack: store -2*m (exact bf16 scale) K-MAJOR in global: yT[chunk][row][8]
template<int C>
DEV void pack_mem_dev(const float* __restrict__ x, u16* __restrict__ yT, float* __restrict__ nrm,
                      int bid, int tid) {
  int row = bid * 4 + (tid >> 6), lane = tid & 63;
  constexpr int E = C / 64;
  const float* src = x + (size_t)row * C + lane * E;
  float s = 0.f;
  if constexpr (E == 4) {
    float4 v = *(const float4*)src;
    s = v.x * v.x + v.y * v.y + v.z * v.z + v.w * v.w;
    u32 lo = (u32)f2bf(-2.f * v.x) | ((u32)f2bf(-2.f * v.y) << 16);
    u32 hi = (u32)f2bf(-2.f * v.z) | ((u32)f2bf(-2.f * v.w) << 16);
    size_t di = ((size_t)(lane >> 1) * MM + row) * 8 + (lane & 1) * 4;
    *(uint2*)(yT + di) = make_uint2(lo, hi);
  } else {
    float2 v = *(const float2*)src;
    s = v.x * v.x + v.y * v.y;
    size_t di = ((size_t)(lane >> 2) * MM + row) * 8 + (lane & 3) * 2;
    *(u32*)(yT + di) = (u32)f2bf(-2.f * v.x) | ((u32)f2bf(-2.f * v.y) << 16);
  }
#pragma unroll
  for (int m = 1; m < 64; m <<= 1) s += __shfl_xor(s, m);
  if (lane == 0) nrm[row] = s;
}

template<int C>
DEV void pack_q_dev(const float* __restrict__ q, u16* __restrict__ qfb, int bid, int tid) {
  int g = bid * 256 + tid;
  int n = g % NQ;
  int cc = g / NQ;
  int b = n / PP, p = n % PP;
  int c0 = cc * 8;
  const float* src = q + ((size_t)b * C + c0) * PP + p;
  s8v o;
#pragma unroll
  for (int i = 0; i < 8; ++i) o[i] = (short)f2bf(src[(size_t)i * PP]);
  ((s8v*)qfb)[((size_t)n * C + c0) >> 3] = o;
}

__global__ __launch_bounds__(256) void k_prep(
    const float* __restrict__ q2, const float* __restrict__ q3,
    const float* __restrict__ mem2, const float* __restrict__ mem3,
    const float* __restrict__ icov2, const float* __restrict__ icov3,
    u16* __restrict__ qf2b, u16* __restrict__ qf3b,
    u16* __restrict__ m2t, u16* __restrict__ m3t,
    u16* __restrict__ ic2b, u16* __restrict__ ic3b,
    float* __restrict__ mn2, float* __restrict__ mn3) {
  int bid = blockIdx.x, tid = threadIdx.x;
  if (bid < 2048)       pack_mem_dev<128>(mem2, m2t, mn2, bid, tid);
  else if (bid < 4096)  pack_mem_dev<256>(mem3, m3t, mn3, bid - 2048, tid);
  else if (bid < 4104)  pack_bf16_dev(icov2, ic2b, bid - 4096, tid);
  else if (bid < 4136)  pack_bf16_dev(icov3, ic3b, bid - 4104, tid);
  else if (bid < 4920)  pack_q_dev<128>(q2, qf2b, bid - 4136, tid);
  else                  pack_q_dev<256>(q3, qf3b, bid - 4920, tid);
}

// ================= fused distances + per-row 5 smallest d2' =================
// R17 body + MT=64 (NT=16): the ~1.4us/tile-round FIXED cost (invariant across
// R11-R17) is halved in count; per-round work doubles (acc[2cg][2mb], 2 ds_reads
// feed 4 MFMAs per kk, 8 scan8/tile). 2x32KB LDS buffers -> 2 blocks/CU.
template<int C, int NSPLIT>
DEV void score_body(const u16* __restrict__ qf, const u16* __restrict__ memT,
                    const float* __restrict__ mn, float* __restrict__ kp,
                    float* __restrict__ qn,
                    int bid2, u16* __restrict__ BsB, float* __restrict__ mnSB, int tid) {
  constexpr int MT = 64, MS = MM / NSPLIT, NT = MS / MT;   // NT = 16
  constexpr int CHUNKS = C / 8;           // 16B chunks per mem row (32 / 16)
  constexpr int PAIRS = CHUNKS / 2;       // K-groups of 16 elems (16 / 8)
  constexpr int SIT = (MT * CHUNKS) / 256;// gl2lds16 per thread per tile (8 / 4)
  constexpr int P = SIT + 1;              // + mn load (9 / 5)
  constexpr int BSTRIDE = 16384;          // u16 per LDS buffer (32KB, sized for C=256)
  constexpr int QROWS = 4 * 64;           // 4 waves x 64 q-cols = 256
  constexpr int RT = NQ / QROWS;          // 49 exactly
  static_assert(NT >= 3, "pipeline needs NT>=3");

  const int wave = tid >> 6, lane = tid & 63;
  const int l31 = lane & 31, kh = lane >> 5;
  const int rt = bid2 % RT, split = bid2 / RT;
  const int row0 = rt * QROWS, mb0 = split * MS;

  // q fragments (B operand; loop-invariant) -> registers, pinned. 2 col-groups.
  bf8v qv[2][PAIRS];
#pragma unroll
  for (int cg = 0; cg < 2; ++cg)
#pragma unroll
    for (int kk = 0; kk < PAIRS; ++kk)
      qv[cg][kk] = *(const bf8v*)(qf + (size_t)(row0 + wave * 64 + cg * 32 + l31) * C + kk * 16 + kh * 8);
#pragma unroll
  for (int cg = 0; cg < 2; ++cg)
#pragma unroll
    for (int kk = 0; kk < PAIRS; ++kk)
      asm volatile("" : "+v"(qv[cg][kk]));

  // free q-norm: lane holds K-half kh of q-rows (row0+wave*64+cg*32+l31)
  if (split == 0) {
#pragma unroll
    for (int cg = 0; cg < 2; ++cg) {
      float s = 0.f;
#pragma unroll
      for (int kk = 0; kk < PAIRS; ++kk)
#pragma unroll
        for (int i = 0; i < 8; ++i) { float v = (float)qv[cg][kk][i]; s = fmaf(v, v, s); }
      s += __shfl_xor(s, 32);
      if (lane < 32) qn[row0 + wave * 64 + cg * 32 + l31] = s;
    }
  }

  // staging: lane = row (64 rows), chunk cp = wave + it*4; wave-uniform LDS base ok
  auto STAGE = [&](int buf, int t) {   // exactly P vmem ops per thread
    const int mrow0 = mb0 + t * MT;
    u16* Bs = BsB + buf * BSTRIDE;
#pragma unroll
    for (int it = 0; it < SIT; ++it) {
      int cp = wave + it * 4;
      gl2lds16(memT + ((size_t)cp * MM + mrow0 + lane) * 8,
               Bs + cp * 512 + lane * 8);
    }
    gl2lds4(mn + mrow0 + lane, mnSB + buf * 64 + lane);   // dup across waves: benign
  };

  float t0 = 1e30f, t1 = 1e30f, t2 = 1e30f, t3 = 1e30f, t4 = 1e30f;   // cg=0
  float u0 = 1e30f, u1 = 1e30f, u2 = 1e30f, u3 = 1e30f, u4 = 1e30f;   // cg=1

  auto CE = [](float& a, float& b) { float lo = fminf(a, b), hi = fmaxf(a, b); a = lo; b = hi; };

  // sort 8 candidates (19-CE Batcher network), then positional merge into a0..a4
  auto scan8 = [&](float x0, float x1, float x2, float x3,
                   float x4, float x5, float x6, float x7,
                   float& a0, float& a1, float& a2, float& a3, float& a4) {
    CE(x0, x1); CE(x2, x3); CE(x4, x5); CE(x6, x7);
    CE(x0, x2); CE(x1, x3); CE(x4, x6); CE(x5, x7);
    CE(x1, x2); CE(x5, x6); CE(x0, x4); CE(x3, x7);
    CE(x1, x5); CE(x2, x6);
    CE(x1, x4); CE(x3, x6);
    CE(x2, x4); CE(x3, x5);
    CE(x3, x4);
    ins5(x0, a0, a1, a2, a3, a4);
    float v, hi;
    v = x1;
    hi = fmaxf(v, a1); a1 = fminf(v, a1); v = hi;
    hi = fmaxf(v, a2); a2 = fminf(v, a2); v = hi;
    hi = fmaxf(v, a3); a3 = fminf(v, a3); v = hi;
    a4 = fminf(v, a4);
    v = x2;
    hi = fmaxf(v, a2); a2 = fminf(v, a2); v = hi;
    hi = fmaxf(v, a3); a3 = fminf(v, a3); v = hi;
    a4 = fminf(v, a4);
    v = x3;
    hi = fmaxf(v, a3); a3 = fminf(v, a3); v = hi;
    a4 = fminf(v, a4);
    a4 = fminf(a4, x4);
  };

  auto COMPUTE = [&](int cur) {
    f16v acc[2][2];   // [cg][mb: 32-row half]
#pragma unroll
    for (int g = 0; g < 4; ++g)
#pragma unroll
      for (int mb = 0; mb < 2; ++mb) {
        f4v m4 = *(const f4v*)(mnSB + cur * 64 + mb * 32 + g * 8 + kh * 4);
#pragma unroll
        for (int cg = 0; cg < 2; ++cg) {
          acc[cg][mb][4 * g + 0] = m4[0]; acc[cg][mb][4 * g + 1] = m4[1];
          acc[cg][mb][4 * g + 2] = m4[2]; acc[cg][mb][4 * g + 3] = m4[3];
        }
      }
    // chunk c = kk*2+kh at c*512 u16; row = mb*32+l31 -> +mb*256+l31*8 u16
    const u16* Bb = BsB + cur * BSTRIDE + l31 * 8 + kh * 512;
#pragma unroll
    for (int kk = 0; kk < PAIRS; ++kk) {
      bf8v mf0 = *(const bf8v*)(Bb + kk * 1024);
      bf8v mf1 = *(const bf8v*)(Bb + kk * 1024 + 256);
      acc[0][0] = __builtin_amdgcn_mfma_f32_32x32x16_bf16(mf0, qv[0][kk], acc[0][0], 0, 0, 0);
      acc[1][0] = __builtin_amdgcn_mfma_f32_32x32x16_bf16(mf0, qv[1][kk], acc[1][0], 0, 0, 0);
      acc[0][1] = __builtin_amdgcn_mfma_f32_32x32x16_bf16(mf1, qv[0][kk], acc[0][1], 0, 0, 0);
      acc[1][1] = __builtin_amdgcn_mfma_f32_32x32x16_bf16(mf1, qv[1][kk], acc[1][1], 0, 0, 0);
    }
#pragma unroll
    for (int mb = 0; mb < 2; ++mb) {
      scan8(acc[0][mb][0], acc[0][mb][1], acc[0][mb][2], acc[0][mb][3],
            acc[0][mb][4], acc[0][mb][5], acc[0][mb][6], acc[0][mb][7], t0, t1, t2, t3, t4);
      scan8(acc[0][mb][8], acc[0][mb][9], acc[0][mb][10], acc[0][mb][11],
            acc[0][mb][12], acc[0][mb][13], acc[0][mb][14], acc[0][mb][15], t0, t1, t2, t3, t4);
      scan8(acc[1][mb][0], acc[1][mb][1], acc[1][mb][2], acc[1][mb][3],
            acc[1][mb][4], acc[1][mb][5], acc[1][mb][6], acc[1][mb][7], u0, u1, u2, u3, u4);
      scan8(acc[1][mb][8], acc[1][mb][9], acc[1][mb][10], acc[1][mb][11],
            acc[1][mb][12], acc[1][mb][13], acc[1][mb][14], acc[1][mb][15], u0, u1, u2, u3, u4);
    }
  };

  STAGE(0, 0); STAGE(1, 1);   // 2 tiles in flight (2P outstanding)

  for (int t = 0; t < NT - 2; ++t) {
    const int cur = t & 1;
    wait_vm<P>();                       // tile t landed; t+1 still flying
    __builtin_amdgcn_sched_barrier(0);
    __builtin_amdgcn_s_barrier();
    __builtin_amdgcn_sched_barrier(0);
    COMPUTE(cur);
    __builtin_amdgcn_sched_barrier(0);
    __builtin_amdgcn_s_barrier();       // all waves done reading Bs[cur]
    __builtin_amdgcn_sched_barrier(0);
    STAGE(cur, t + 2);                  // refill freed buffer
  }
  {
    wait_vm<P>();
    __builtin_amdgcn_sched_barrier(0);
    __builtin_amdgcn_s_barrier();
    __builtin_amdgcn_sched_barrier(0);
    COMPUTE((NT - 2) & 1);
    __builtin_amdgcn_sched_barrier(0);
    __builtin_amdgcn_s_barrier();
    wait_vm<0>();
    __builtin_amdgcn_sched_barrier(0);
    __builtin_amdgcn_s_barrier();
    __builtin_amdgcn_sched_barrier(0);
    COMPUTE((NT - 1) & 1);
  }

  // per cg: merge the 2 lanes holding the same q-col (lane, lane+32), write
  {
    float r0 = __shfl_xor(t0, 32), r1 = __shfl_xor(t1, 32), r2 = __shfl_xor(t2, 32),
          r3 = __shfl_xor(t3, 32), r4 = __shfl_xor(t4, 32);
    ins5(r0, t0, t1, t2, t3, t4);
    ins5(r1, t0, t1, t2, t3, t4);
    ins5(r2, t0, t1, t2, t3, t4);
    ins5(r3, t0, t1, t2, t3, t4);
    ins5(r4, t0, t1, t2, t3, t4);
    r0 = __shfl_xor(u0, 32); r1 = __shfl_xor(u1, 32); r2 = __shfl_xor(u2, 32);
    r3 = __shfl_xor(u3, 32); r4 = __shfl_xor(u4, 32);
    ins5(r0, u0, u1, u2, u3, u4);
    ins5(r1, u0, u1, u2, u3, u4);
    ins5(r2, u0, u1, u2, u3, u4);
    ins5(r3, u0, u1, u2, u3, u4);
    ins5(r4, u0, u1, u2, u3, u4);
  }
  if (lane < 32) {
    int g0 = row0 + wave * 64 + l31;
    float* o = kp + ((size_t)g0 * NSPLIT + split) * 5;
    o[0] = t0; o[1] = t1; o[2] = t2; o[3] = t3; o[4] = t4;
    float* o1 = kp + ((size_t)(g0 + 32) * NSPLIT + split) * 5;
    o1[0] = u0; o1[1] = u1; o1[2] = u2; o1[3] = u3; o1[4] = u4;
  }
}

// ================= Mahalanobis body (co-dispatched with score) =================
template<int C>
DEV void maha_dev(const u16* __restrict__ qfb, const float* __restrict__ mu,
                  const u16* __restrict__ icovb, float* __restrict__ mh,
                  u16* As, float* muS, int bid, int tid) {
  constexpr int QT = 64, KCH = C / 8;
  int wave = tid >> 6, lane = tid & 63;
  int row0 = bid * QT;

  for (int i = tid; i < C; i += 256) muS[i] = mu[i];
  __syncthreads();
  for (int u = tid; u < QT * KCH; u += 256) {
    int r = u / KCH, cc = u % KCH;
    bf8v v = *(const bf8v*)(qfb + (size_t)(row0 + r) * C + cc * 8);
    s8v d;
#pragma unroll
    for (int i = 0; i < 8; ++i) d[i] = (short)f2bf((float)v[i] - muS[cc * 8 + i]);
    *(s8v*)(As + r * C + ((cc ^ (r & 7)) << 3)) = d;
  }
  __syncthreads();

  int arow = wave * 16 + (lane & 15);
  int kb = lane >> 4;
  float mm[4] = {0.f, 0.f, 0.f, 0.f};
#pragma unroll
  for (int cb = 0; cb < C / 16; ++cb) {
    f4v acc = (f4v){0.f, 0.f, 0.f, 0.f};
    int bcol = cb * 16 + (lane & 15);
#pragma unroll
    for (int kk = 0; kk < C / 32; ++kk) {
      int kc = kk * 4 + kb;
      bf8v a = *(const bf8v*)(As + arow * C + ((kc ^ (arow & 7)) << 3));
      bf8v b = *(const bf8v*)(icovb + (size_t)bcol * C + kc * 8);
      acc = __builtin_amdgcn_mfma_f32_16x16x32_bf16(a, b, acc, 0, 0, 0);
    }
#pragma unroll
    for (int r = 0; r < 4; ++r) {
      int row = wave * 16 + (lane >> 4) * 4 + r;
      int col = cb * 16 + (lane & 15);
      float dv = bf2f(As[row * C + (((col >> 3) ^ (row & 7)) << 3) + (col & 7)]);
      mm[r] += acc[r] * dv;
    }
  }
#pragma unroll
  for (int r = 0; r < 4; ++r) {
    float v = mm[r];
    v += __shfl_xor(v, 1); v += __shfl_xor(v, 2);
    v += __shfl_xor(v, 4); v += __shfl_xor(v, 8);
    if ((lane & 15) == 0)
      mh[row0 + wave * 16 + (lane >> 4) * 4 + r] = sqrtf(fmaxf(v, EPSF));
  }
}

// fused launcher: bid<784: score (even->C=256, odd->C=128); bid>=784: maha
__global__ __launch_bounds__(256, 2) void k_score_f(
    const u16* __restrict__ qf3, const u16* __restrict__ m3t,
    const float* __restrict__ mn3, float* __restrict__ kp3, float* __restrict__ qn3,
    const u16* __restrict__ qf2, const u16* __restrict__ m2t,
    const float* __restrict__ mn2, float* __restrict__ kp2, float* __restrict__ qn2,
    const float* __restrict__ mean2, const float* __restrict__ mean3,
    const u16* __restrict__ ic2b, const u16* __restrict__ ic3b,
    float* __restrict__ mh2, float* __restrict__ mh3) {
  __shared__ alignas(16) u16 Bs[2 * 16384];     // 64KB (score dbuf; maha As aliases)
  __shared__ alignas(16) float mnS[2 * 64];
  __shared__ alignas(16) float muX[256];        // maha mu scratch
  int bid = blockIdx.x, tid = threadIdx.x;
  if (bid < 784) {
    if (bid & 1) score_body<128, 8>(qf2, m2t, mn2, kp2, qn2, bid >> 1, Bs, mnS, tid);
    else         score_body<256, 8>(qf3, m3t, mn3, kp3, qn3, bid >> 1, Bs, mnS, tid);
  } else {
    int b2 = bid - 784;
    if (b2 < 196) maha_dev<128>(qf2, mean2, ic2b, mh2, Bs, muX, b2, tid);
    else          maha_dev<256>(qf3, mean3, ic3b, mh3, Bs, muX, b2 - 196, tid);
  }
}

// ================= combine: merge knn splits (+qn), build maps =================
template<int S>
DEV float knn_merge(const float* kp, int n, float qv) {
  float t0 = 1e30f, t1 = 1e30f, t2 = 1e30f, t3 = 1e30f, t4 = 1e30f;
  const float* p = kp + (size_t)n * S * 5;
#pragma unroll
  for (int i = 0; i < S * 5; ++i) ins5(p[i], t0, t1, t2, t3, t4);
  return 0.2f * (sqrtf(fmaxf(t0 + qv, EPSF)) + sqrtf(fmaxf(t1 + qv, EPSF)) +
                 sqrtf(fmaxf(t2 + qv, EPSF)) + sqrtf(fmaxf(t3 + qv, EPSF)) +
                 sqrtf(fmaxf(t4 + qv, EPSF)));
}

__global__ __launch_bounds__(256) void k_combine(
    const float* __restrict__ kp2, const float* __restrict__ kp3,
    const float* __restrict__ qn2, const float* __restrict__ qn3,
    const float* __restrict__ mh2, const float* __restrict__ mh3,
    float* __restrict__ out) {
  int n = blockIdx.x * 256 + threadIdx.x;
  float m2v = 0.5f * (knn_merge<8>(kp2, n, qn2[n]) + mh2[n]);
  float m3v = 0.5f * (knn_merge<8>(kp3, n, qn3[n]) + mh3[n]);
  out[16 + n] = 0.5f * (m2v + m3v);
  out[16 + NQ + n] = m2v;
  out[16 + 2 * NQ + n] = m3v;
}

// ================= per-image top-10 mean over 784-pixel map =================
__global__ __launch_bounds__(256) void k_top10(const float* __restrict__ comb, float* __restrict__ pred) {
  __shared__ float vals[1024];
  __shared__ float rv[256];
  __shared__ int ri[256];
  __shared__ float ssum;
  int b = blockIdx.x, tid = threadIdx.x;
  for (int i = tid; i < 1024; i += 256) vals[i] = (i < PP) ? comb[b * PP + i] : -1e30f;
  if (tid == 0) ssum = 0.f;
  __syncthreads();
  for (int it = 0; it < 10; ++it) {
    float bv = -1e30f; int bi = 0;
    for (int i = tid; i < 1024; i += 256) { float v = vals[i]; if (v > bv) { bv = v; bi = i; } }
    rv[tid] = bv; ri[tid] = bi;
    __syncthreads();
    for (int s = 128; s; s >>= 1) {
      if (tid < s && rv[tid + s] > rv[tid]) { rv[tid] = rv[tid + s]; ri[tid] = ri[tid + s]; }
      __syncthreads();
    }
    if (tid == 0) { ssum += rv[0]; vals[ri[0]] = -1e30f; }
    __syncthreads();
  }
  if (tid == 0) pred[b] = ssum * 0.1f;
}

extern "C" void kernel_launch(void* const* d_in, const int* in_sizes, int n_in,
                              void* d_out, int out_size, void* d_ws, size_t ws_size,
                              hipStream_t stream) {
  const float* q2    = (const float*)d_in[0];
  const float* q3    = (const float*)d_in[1];
  const float* mem2  = (const float*)d_in[2];
  const float* mem3  = (const float*)d_in[3];
  const float* mean2 = (const float*)d_in[4];
  const float* mean3 = (const float*)d_in[5];
  const float* icov2 = (const float*)d_in[6];
  const float* icov3 = (const float*)d_in[7];
  float* out = (float*)d_out;

  char* w = (char*)d_ws;
  auto alloc = [&](size_t bytes) { void* p = (void*)w; w += (bytes + 255) & ~(size_t)255; return p; };
  u16* qf2b = (u16*)alloc((size_t)NQ * 128 * 2);
  u16* qf3b = (u16*)alloc((size_t)NQ * 256 * 2);
  u16* m2t  = (u16*)alloc((size_t)MM * 128 * 2);
  u16* m3t  = (u16*)alloc((size_t)MM * 256 * 2);
  u16* ic2b = (u16*)alloc((size_t)128 * 128 * 2);
  u16* ic3b = (u16*)alloc((size_t)256 * 256 * 2);
  float* qn2 = (float*)alloc((size_t)NQ * 4);
  float* qn3 = (float*)alloc((size_t)NQ * 4);
  float* mn2 = (float*)alloc((size_t)MM * 4);
  float* mn3 = (float*)alloc((size_t)MM * 4);
  float* kp2 = (float*)alloc((size_t)NQ * 8 * 5 * 4);
  float* kp3 = (float*)alloc((size_t)NQ * 8 * 5 * 4);
  float* mh2 = (float*)alloc((size_t)NQ * 4);
  float* mh3 = (float*)alloc((size_t)NQ * 4);

  k_prep<<<6488, 256, 0, stream>>>(q2, q3, mem2, mem3, icov2, icov3,
                                   qf2b, qf3b, m2t, m3t, ic2b, ic3b, mn2, mn3);

  // fused score (+q-norms) + co-dispatched maha: 784 score blocks + 392 maha blocks
  k_score_f<<<1176, 256, 0, stream>>>(qf3b, m3t, mn3, kp3, qn3,
                                      qf2b, m2t, mn2, kp2, qn2,
                                      mean2, mean3, ic2b, ic3b, mh2, mh3);

  k_combine<<<NQ / 256, 256, 0, stream>>>(kp2, kp3, qn2, qn3, mh2, mh3, out);
  k_top10<<<16, 256, 0, stream>>>(out + 16, out);

  (void)in_sizes; (void)n_in; (void)out_size; (void)ws_size;
}

// Round 19
// 168.918 us; speedup vs baseline: 1.6407x; 1.0001x over previous
//
#include <hip/hip_runtime.h>

typedef unsigned short u16;
typedef unsigned int u32;
typedef __attribute__((ext_vector_type(8))) __bf16 bf8v;    // MFMA A/B operand (8 bf16)
typedef __attribute__((ext_vector_type(8))) short s8v;      // same bits, for packing
typedef __attribute__((ext_vector_type(4))) float f4v;
typedef __attribute__((ext_vector_type(16))) float f16v;    // 32x32 MFMA C/D

#define DEV static __device__ __forceinline__

constexpr int NQ = 12544;   // B*H*W = 16*28*28
constexpr int MM = 8192;    // memory bank rows
constexpr int PP = 784;     // H*W
constexpr float EPSF = 1e-12f;

DEV u16 f2bf(float f) {  // RNE f32 -> bf16 (inputs are finite normals)
  u32 u = __float_as_uint(f);
  return (u16)((u + 0x7FFFu + ((u >> 16) & 1u)) >> 16);
}
DEV float bf2f(u16 h) { return __uint_as_float((u32)h << 16); }

DEV void gl2lds16(const u16* g, u16* l) {
  __builtin_amdgcn_global_load_lds(
      (const __attribute__((address_space(1))) unsigned int*)(g),
      (__attribute__((address_space(3))) unsigned int*)(l), 16, 0, 0);
}
DEV void gl2lds4(const float* g, float* l) {
  __builtin_amdgcn_global_load_lds(
      (const __attribute__((address_space(1))) unsigned int*)(g),
      (__attribute__((address_space(3))) unsigned int*)(l), 4, 0, 0);
}

template<int N> DEV void wait_vm() {   // counted vmcnt (T4): literal immediates only
  if constexpr (N == 0) asm volatile("s_waitcnt vmcnt(0)" ::: "memory");
  else if constexpr (N == 5) asm volatile("s_waitcnt vmcnt(5)" ::: "memory");
  else if constexpr (N == 9) asm volatile("s_waitcnt vmcnt(9)" ::: "memory");
  else static_assert(N == 0, "unsupported vmcnt");
}

// branchless sorted insert: keep 5 smallest in a0<=..<=a4
DEV void ins5(float v, float& a0, float& a1, float& a2, float& a3, float& a4) {
  float hi;
  hi = fmaxf(v, a0); a0 = fminf(v, a0); v = hi;
  hi = fmaxf(v, a1); a1 = fminf(v, a1); v = hi;
  hi = fmaxf(v, a2); a2 = fminf(v, a2); v = hi;
  hi = fmaxf(v, a3); a3 = fminf(v, a3); v = hi;
  a4 = fminf(v, a4);
}

// ================= fused prep =================
DEV void pack_bf16_dev(const float* __restrict__ x, u16* __restrict__ y, int bid, int tid) {
  int g = bid * 256 + tid;
  const float4* px = (const float4*)x + (size_t)g * 2;
  float4 a = px[0], b = px[1];
  s8v o;
  o[0] = (short)f2bf(a.x); o[1] = (short)f2bf(a.y); o[2] = (short)f2bf(a.z); o[3] = (short)f2bf(a.w);
  o[4] = (short)f2bf(b.x); o[5] = (short)f2bf(b.y); o[6] = (short)f2bf(b.z); o[7] = (short)f2bf(b.w);
  ((s8v*)y)[g] = o;
}

// mem pack: store -2*m (exact bf16 scale) K-MAJOR in global: yT[chunk][row][8]
template<int C>
DEV void pack_mem_dev(const float* __restrict__ x, u16* __restrict__ yT, float* __restrict__ nrm,
                      int bid, int tid) {
  int row = bid * 4 + (tid >> 6), lane = tid & 63;
  constexpr int E = C / 64;
  const float* src = x + (size_t)row * C + lane * E;
  float s = 0.f;
  if constexpr (E == 4) {
    float4 v = *(const float4*)src;
    s = v.x * v.x + v.y * v.y + v.z * v.z + v.w * v.w;
    u32 lo = (u32)f2bf(-2.f * v.x) | ((u32)f2bf(-2.f * v.y) << 16);
    u32 hi = (u32)f2bf(-2.f * v.z) | ((u32)f2bf(-2.f * v.w) << 16);
    size_t di = ((size_t)(lane >> 1) * MM + row) * 8 + (lane & 1) * 4;
    *(uint2*)(yT + di) = make_uint2(lo, hi);
  } else {
    float2 v = *(const float2*)src;
    s = v.x * v.x + v.y * v.y;
    size_t di = ((size_t)(lane >> 2) * MM + row) * 8 + (lane & 3) * 2;
    *(u32*)(yT + di) = (u32)f2bf(-2.f * v.x) | ((u32)f2bf(-2.f * v.y) << 16);
  }
#pragma unroll
  for (int m = 1; m < 64; m <<= 1) s += __shfl_xor(s, m);
  if (lane == 0) nrm[row] = s;
}

template<int C>
DEV void pack_q_dev(const float* __restrict__ q, u16* __restrict__ qfb, int bid, int tid) {
  int g = bid * 256 + tid;
  int n = g % NQ;
  int cc = g / NQ;
  int b = n / PP, p = n % PP;
  int c0 = cc * 8;
  const float* src = q + ((size_t)b * C + c0) * PP + p;
  s8v o;
#pragma unroll
  for (int i = 0; i < 8; ++i) o[i] = (short)f2bf(src[(size_t)i * PP]);
  ((s8v*)qfb)[((size_t)n * C + c0) >> 3] = o;
}

__global__ __launch_bounds__(256) void k_prep(
    const float* __restrict__ q2, const float* __restrict__ q3,
    const float* __restrict__ mem2, const float* __restrict__ mem3,
    const float* __restrict__ icov2, const float* __restrict__ icov3,
    u16* __restrict__ qf2b, u16* __restrict__ qf3b,
    u16* __restrict__ m2t, u16* __restrict__ m3t,
    u16* __restrict__ ic2b, u16* __restrict__ ic3b,
    float* __restrict__ mn2, float* __restrict__ mn3) {
  int bid = blockIdx.x, tid = threadIdx.x;
  if (bid < 2048)       pack_mem_dev<128>(mem2, m2t, mn2, bid, tid);
  else if (bid < 4096)  pack_mem_dev<256>(mem3, m3t, mn3, bid - 2048, tid);
  else if (bid < 4104)  pack_bf16_dev(icov2, ic2b, bid - 4096, tid);
  else if (bid < 4136)  pack_bf16_dev(icov3, ic3b, bid - 4104, tid);
  else if (bid < 4920)  pack_q_dev<128>(q2, qf2b, bid - 4136, tid);
  else                  pack_q_dev<256>(q3, qf3b, bid - 4920, tid);
}

// ================= fused distances + per-row 5 smallest d2' =================
// R18 body unchanged; launcher now XCD-pins splits (bid&7 == split -> all blocks
// touching a given mem slice land on ONE XCD; its 4MB L2 holds the slice once).
template<int C, int NSPLIT>
DEV void score_body(const u16* __restrict__ qf, const u16* __restrict__ memT,
                    const float* __restrict__ mn, float* __restrict__ kp,
                    float* __restrict__ qn,
                    int rt, int split, u16* __restrict__ BsB, float* __restrict__ mnSB, int tid) {
  constexpr int MT = 64, MS = MM / NSPLIT, NT = MS / MT;   // NT = 16
  constexpr int CHUNKS = C / 8;           // 16B chunks per mem row (32 / 16)
  constexpr int PAIRS = CHUNKS / 2;       // K-groups of 16 elems (16 / 8)
  constexpr int SIT = (MT * CHUNKS) / 256;// gl2lds16 per thread per tile (8 / 4)
  constexpr int P = SIT + 1;              // + mn load (9 / 5)
  constexpr int BSTRIDE = 16384;          // u16 per LDS buffer (32KB, sized for C=256)
  constexpr int QROWS = 4 * 64;           // 4 waves x 64 q-cols = 256
  static_assert(NT >= 3, "pipeline needs NT>=3");

  const int wave = tid >> 6, lane = tid & 63;
  const int l31 = lane & 31, kh = lane >> 5;
  const int row0 = rt * QROWS, mb0 = split * MS;

  // q fragments (B operand; loop-invariant) -> registers, pinned. 2 col-groups.
  bf8v qv[2][PAIRS];
#pragma unroll
  for (int cg = 0; cg < 2; ++cg)
#pragma unroll
    for (int kk = 0; kk < PAIRS; ++kk)
      qv[cg][kk] = *(const bf8v*)(qf + (size_t)(row0 + wave * 64 + cg * 32 + l31) * C + kk * 16 + kh * 8);
#pragma unroll
  for (int cg = 0; cg < 2; ++cg)
#pragma unroll
    for (int kk = 0; kk < PAIRS; ++kk)
      asm volatile("" : "+v"(qv[cg][kk]));

  // free q-norm: lane holds K-half kh of q-rows (row0+wave*64+cg*32+l31)
  if (split == 0) {
#pragma unroll
    for (int cg = 0; cg < 2; ++cg) {
      float s = 0.f;
#pragma unroll
      for (int kk = 0; kk < PAIRS; ++kk)
#pragma unroll
        for (int i = 0; i < 8; ++i) { float v = (float)qv[cg][kk][i]; s = fmaf(v, v, s); }
      s += __shfl_xor(s, 32);
      if (lane < 32) qn[row0 + wave * 64 + cg * 32 + l31] = s;
    }
  }

  // staging: lane = row (64 rows), chunk cp = wave + it*4; wave-uniform LDS base ok
  auto STAGE = [&](int buf, int t) {   // exactly P vmem ops per thread
    const int mrow0 = mb0 + t * MT;
    u16* Bs = BsB + buf * BSTRIDE;
#pragma unroll
    for (int it = 0; it < SIT; ++it) {
      int cp = wave + it * 4;
      gl2lds16(memT + ((size_t)cp * MM + mrow0 + lane) * 8,
               Bs + cp * 512 + lane * 8);
    }
    gl2lds4(mn + mrow0 + lane, mnSB + buf * 64 + lane);   // dup across waves: benign
  };

  float t0 = 1e30f, t1 = 1e30f, t2 = 1e30f, t3 = 1e30f, t4 = 1e30f;   // cg=0
  float u0 = 1e30f, u1 = 1e30f, u2 = 1e30f, u3 = 1e30f, u4 = 1e30f;   // cg=1

  auto CE = [](float& a, float& b) { float lo = fminf(a, b), hi = fmaxf(a, b); a = lo; b = hi; };

  // sort 8 candidates (19-CE Batcher network), then positional merge into a0..a4
  auto scan8 = [&](float x0, float x1, float x2, float x3,
                   float x4, float x5, float x6, float x7,
                   float& a0, float& a1, float& a2, float& a3, float& a4) {
    CE(x0, x1); CE(x2, x3); CE(x4, x5); CE(x6, x7);
    CE(x0, x2); CE(x1, x3); CE(x4, x6); CE(x5, x7);
    CE(x1, x2); CE(x5, x6); CE(x0, x4); CE(x3, x7);
    CE(x1, x5); CE(x2, x6);
    CE(x1, x4); CE(x3, x6);
    CE(x2, x4); CE(x3, x5);
    CE(x3, x4);
    ins5(x0, a0, a1, a2, a3, a4);
    float v, hi;
    v = x1;
    hi = fmaxf(v, a1); a1 = fminf(v, a1); v = hi;
    hi = fmaxf(v, a2); a2 = fminf(v, a2); v = hi;
    hi = fmaxf(v, a3); a3 = fminf(v, a3); v = hi;
    a4 = fminf(v, a4);
    v = x2;
    hi = fmaxf(v, a2); a2 = fminf(v, a2); v = hi;
    hi = fmaxf(v, a3); a3 = fminf(v, a3); v = hi;
    a4 = fminf(v, a4);
    v = x3;
    hi = fmaxf(v, a3); a3 = fminf(v, a3); v = hi;
    a4 = fminf(v, a4);
    a4 = fminf(a4, x4);
  };

  auto COMPUTE = [&](int cur) {
    f16v acc[2][2];   // [cg][mb: 32-row half]
#pragma unroll
    for (int g = 0; g < 4; ++g)
#pragma unroll
      for (int mb = 0; mb < 2; ++mb) {
        f4v m4 = *(const f4v*)(mnSB + cur * 64 + mb * 32 + g * 8 + kh * 4);
#pragma unroll
        for (int cg = 0; cg < 2; ++cg) {
          acc[cg][mb][4 * g + 0] = m4[0]; acc[cg][mb][4 * g + 1] = m4[1];
          acc[cg][mb][4 * g + 2] = m4[2]; acc[cg][mb][4 * g + 3] = m4[3];
        }
      }
    const u16* Bb = BsB + cur * BSTRIDE + l31 * 8 + kh * 512;
#pragma unroll
    for (int kk = 0; kk < PAIRS; ++kk) {
      bf8v mf0 = *(const bf8v*)(Bb + kk * 1024);
      bf8v mf1 = *(const bf8v*)(Bb + kk * 1024 + 256);
      acc[0][0] = __builtin_amdgcn_mfma_f32_32x32x16_bf16(mf0, qv[0][kk], acc[0][0], 0, 0, 0);
      acc[1][0] = __builtin_amdgcn_mfma_f32_32x32x16_bf16(mf0, qv[1][kk], acc[1][0], 0, 0, 0);
      acc[0][1] = __builtin_amdgcn_mfma_f32_32x32x16_bf16(mf1, qv[0][kk], acc[0][1], 0, 0, 0);
      acc[1][1] = __builtin_amdgcn_mfma_f32_32x32x16_bf16(mf1, qv[1][kk], acc[1][1], 0, 0, 0);
    }
#pragma unroll
    for (int mb = 0; mb < 2; ++mb) {
      scan8(acc[0][mb][0], acc[0][mb][1], acc[0][mb][2], acc[0][mb][3],
            acc[0][mb][4], acc[0][mb][5], acc[0][mb][6], acc[0][mb][7], t0, t1, t2, t3, t4);
      scan8(acc[0][mb][8], acc[0][mb][9], acc[0][mb][10], acc[0][mb][11],
            acc[0][mb][12], acc[0][mb][13], acc[0][mb][14], acc[0][mb][15], t0, t1, t2, t3, t4);
      scan8(acc[1][mb][0], acc[1][mb][1], acc[1][mb][2], acc[1][mb][3],
            acc[1][mb][4], acc[1][mb][5], acc[1][mb][6], acc[1][mb][7], u0, u1, u2, u3, u4);
      scan8(acc[1][mb][8], acc[1][mb][9], acc[1][mb][10], acc[1][mb][11],
            acc[1][mb][12], acc[1][mb][13], acc[1][mb][14], acc[1][mb][15], u0, u1, u2, u3, u4);
    }
  };

  STAGE(0, 0); STAGE(1, 1);   // 2 tiles in flight (2P outstanding)

  for (int t = 0; t < NT - 2; ++t) {
    const int cur = t & 1;
    wait_vm<P>();                       // tile t landed; t+1 still flying
    __builtin_amdgcn_sched_barrier(0);
    __builtin_amdgcn_s_barrier();
    __builtin_amdgcn_sched_barrier(0);
    COMPUTE(cur);
    __builtin_amdgcn_sched_barrier(0);
    __builtin_amdgcn_s_barrier();       // all waves done reading Bs[cur]
    __builtin_amdgcn_sched_barrier(0);
    STAGE(cur, t + 2);                  // refill freed buffer
  }
  {
    wait_vm<P>();
    __builtin_amdgcn_sched_barrier(0);
    __builtin_amdgcn_s_barrier();
    __builtin_amdgcn_sched_barrier(0);
    COMPUTE((NT - 2) & 1);
    __builtin_amdgcn_sched_barrier(0);
    __builtin_amdgcn_s_barrier();
    wait_vm<0>();
    __builtin_amdgcn_sched_barrier(0);
    __builtin_amdgcn_s_barrier();
    __builtin_amdgcn_sched_barrier(0);
    COMPUTE((NT - 1) & 1);
  }

  // per cg: merge the 2 lanes holding the same q-col (lane, lane+32), write
  {
    float r0 = __shfl_xor(t0, 32), r1 = __shfl_xor(t1, 32), r2 = __shfl_xor(t2, 32),
          r3 = __shfl_xor(t3, 32), r4 = __shfl_xor(t4, 32);
    ins5(r0, t0, t1, t2, t3, t4);
    ins5(r1, t0, t1, t2, t3, t4);
    ins5(r2, t0, t1, t2, t3, t4);
    ins5(r3, t0, t1, t2, t3, t4);
    ins5(r4, t0, t1, t2, t3, t4);
    r0 = __shfl_xor(u0, 32); r1 = __shfl_xor(u1, 32); r2 = __shfl_xor(u2, 32);
    r3 = __shfl_xor(u3, 32); r4 = __shfl_xor(u4, 32);
    ins5(r0, u0, u1, u2, u3, u4);
    ins5(r1, u0, u1, u2, u3, u4);
    ins5(r2, u0, u1, u2, u3, u4);
    ins5(r3, u0, u1, u2, u3, u4);
    ins5(r4, u0, u1, u2, u3, u4);
  }
  if (lane < 32) {
    int g0 = row0 + wave * 64 + l31;
    float* o = kp + ((size_t)g0 * NSPLIT + split) * 5;
    o[0] = t0; o[1] = t1; o[2] = t2; o[3] = t3; o[4] = t4;
    float* o1 = kp + ((size_t)(g0 + 32) * NSPLIT + split) * 5;
    o1[0] = u0; o1[1] = u1; o1[2] = u2; o1[3] = u3; o1[4] = u4;
  }
}

// ================= Mahalanobis body (co-dispatched with score) =================
template<int C>
DEV void maha_dev(const u16* __restrict__ qfb, const float* __restrict__ mu,
                  const u16* __restrict__ icovb, float* __restrict__ mh,
                  u16* As, float* muS, int bid, int tid) {
  constexpr int QT = 64, KCH = C / 8;
  int wave = tid >> 6, lane = tid & 63;
  int row0 = bid * QT;

  for (int i = tid; i < C; i += 256) muS[i] = mu[i];
  __syncthreads();
  for (int u = tid; u < QT * KCH; u += 256) {
    int r = u / KCH, cc = u % KCH;
    bf8v v = *(const bf8v*)(qfb + (size_t)(row0 + r) * C + cc * 8);
    s8v d;
#pragma unroll
    for (int i = 0; i < 8; ++i) d[i] = (short)f2bf((float)v[i] - muS[cc * 8 + i]);
    *(s8v*)(As + r * C + ((cc ^ (r & 7)) << 3)) = d;
  }
  __syncthreads();

  int arow = wave * 16 + (lane & 15);
  int kb = lane >> 4;
  float mm[4] = {0.f, 0.f, 0.f, 0.f};
#pragma unroll
  for (int cb = 0; cb < C / 16; ++cb) {
    f4v acc = (f4v){0.f, 0.f, 0.f, 0.f};
    int bcol = cb * 16 + (lane & 15);
#pragma unroll
    for (int kk = 0; kk < C / 32; ++kk) {
      int kc = kk * 4 + kb;
      bf8v a = *(const bf8v*)(As + arow * C + ((kc ^ (arow & 7)) << 3));
      bf8v b = *(const bf8v*)(icovb + (size_t)bcol * C + kc * 8);
      acc = __builtin_amdgcn_mfma_f32_16x16x32_bf16(a, b, acc, 0, 0, 0);
    }
#pragma unroll
    for (int r = 0; r < 4; ++r) {
      int row = wave * 16 + (lane >> 4) * 4 + r;
      int col = cb * 16 + (lane & 15);
      float dv = bf2f(As[row * C + (((col >> 3) ^ (row & 7)) << 3) + (col & 7)]);
      mm[r] += acc[r] * dv;
    }
  }
#pragma unroll
  for (int r = 0; r < 4; ++r) {
    float v = mm[r];
    v += __shfl_xor(v, 1); v += __shfl_xor(v, 2);
    v += __shfl_xor(v, 4); v += __shfl_xor(v, 8);
    if ((lane & 15) == 0)
      mh[row0 + wave * 16 + (lane >> 4) * 4 + r] = sqrtf(fmaxf(v, EPSF));
  }
}

// fused launcher with XCD-pinned splits: bid<784: score, bid&7 = split (-> XCD),
// g=bid>>3: layer=g&1, rt=g>>1. bid>=784: maha backfill.
__global__ __launch_bounds__(256, 2) void k_score_f(
    const u16* __restrict__ qf3, const u16* __restrict__ m3t,
    const float* __restrict__ mn3, float* __restrict__ kp3, float* __restrict__ qn3,
    const u16* __restrict__ qf2, const u16* __restrict__ m2t,
    const float* __restrict__ mn2, float* __restrict__ kp2, float* __restrict__ qn2,
    const float* __restrict__ mean2, const float* __restrict__ mean3,
    const u16* __restrict__ ic2b, const u16* __restrict__ ic3b,
    float* __restrict__ mh2, float* __restrict__ mh3) {
  __shared__ alignas(16) u16 Bs[2 * 16384];     // 64KB (score dbuf; maha As aliases)
  __shared__ alignas(16) float mnS[2 * 64];
  __shared__ alignas(16) float muX[256];        // maha mu scratch
  int bid = blockIdx.x, tid = threadIdx.x;
  if (bid < 784) {
    int split = bid & 7, g = bid >> 3;
    int layer = g & 1, rt = g >> 1;             // rt in [0,49)
    if (layer) score_body<128, 8>(qf2, m2t, mn2, kp2, qn2, rt, split, Bs, mnS, tid);
    else       score_body<256, 8>(qf3, m3t, mn3, kp3, qn3, rt, split, Bs, mnS, tid);
  } else {
    int b2 = bid - 784;
    if (b2 < 196) maha_dev<128>(qf2, mean2, ic2b, mh2, Bs, muX, b2, tid);
    else          maha_dev<256>(qf3, mean3, ic3b, mh3, Bs, muX, b2 - 196, tid);
  }
}

// ================= combine: merge knn splits (+qn), build maps =================
template<int S>
DEV float knn_merge(const float* kp, int n, float qv) {
  float t0 = 1e30f, t1 = 1e30f, t2 = 1e30f, t3 = 1e30f, t4 = 1e30f;
  const float* p = kp + (size_t)n * S * 5;
#pragma unroll
  for (int i = 0; i < S * 5; ++i) ins5(p[i], t0, t1, t2, t3, t4);
  return 0.2f * (sqrtf(fmaxf(t0 + qv, EPSF)) + sqrtf(fmaxf(t1 + qv, EPSF)) +
                 sqrtf(fmaxf(t2 + qv, EPSF)) + sqrtf(fmaxf(t3 + qv, EPSF)) +
                 sqrtf(fmaxf(t4 + qv, EPSF)));
}

__global__ __launch_bounds__(256) void k_combine(
    const float* __restrict__ kp2, const float* __restrict__ kp3,
    const float* __restrict__ qn2, const float* __restrict__ qn3,
    const float* __restrict__ mh2, const float* __restrict__ mh3,
    float* __restrict__ out) {
  int n = blockIdx.x * 256 + threadIdx.x;
  float m2v = 0.5f * (knn_merge<8>(kp2, n, qn2[n]) + mh2[n]);
  float m3v = 0.5f * (knn_merge<8>(kp3, n, qn3[n]) + mh3[n]);
  out[16 + n] = 0.5f * (m2v + m3v);
  out[16 + NQ + n] = m2v;
  out[16 + 2 * NQ + n] = m3v;
}

// ================= per-image top-10 mean over 784-pixel map =================
__global__ __launch_bounds__(256) void k_top10(const float* __restrict__ comb, float* __restrict__ pred) {
  __shared__ float vals[1024];
  __shared__ float rv[256];
  __shared__ int ri[256];
  __shared__ float ssum;
  int b = blockIdx.x, tid = threadIdx.x;
  for (int i = tid; i < 1024; i += 256) vals[i] = (i < PP) ? comb[b * PP + i] : -1e30f;
  if (tid == 0) ssum = 0.f;
  __syncthreads();
  for (int it = 0; it < 10; ++it) {
    float bv = -1e30f; int bi = 0;
    for (int i = tid; i < 1024; i += 256) { float v = vals[i]; if (v > bv) { bv = v; bi = i; } }
    rv[tid] = bv; ri[tid] = bi;
    __syncthreads();
    for (int s = 128; s; s >>= 1) {
      if (tid < s && rv[tid + s] > rv[tid]) { rv[tid] = rv[tid + s]; ri[tid] = ri[tid + s]; }
      __syncthreads();
    }
    if (tid == 0) { ssum += rv[0]; vals[ri[0]] = -1e30f; }
    __syncthreads();
  }
  if (tid == 0) pred[b] = ssum * 0.1f;
}

extern "C" void kernel_launch(void* const* d_in, const int* in_sizes, int n_in,
                              void* d_out, int out_size, void* d_ws, size_t ws_size,
                              hipStream_t stream) {
  const float* q2    = (const float*)d_in[0];
  const float* q3    = (const float*)d_in[1];
  const float* mem2  = (const float*)d_in[2];
  const float* mem3  = (const float*)d_in[3];
  const float* mean2 = (const float*)d_in[4];
  const float* mean3 = (const float*)d_in[5];
  const float* icov2 = (const float*)d_in[6];
  const float* icov3 = (const float*)d_in[7];
  float* out = (float*)d_out;

  char* w = (char*)d_ws;
  auto alloc = [&](size_t bytes) { void* p = (void*)w; w += (bytes + 255) & ~(size_t)255; return p; };
  u16* qf2b = (u16*)alloc((size_t)NQ * 128 * 2);
  u16* qf3b = (u16*)alloc((size_t)NQ * 256 * 2);
  u16* m2t  = (u16*)alloc((size_t)MM * 128 * 2);
  u16* m3t  = (u16*)alloc((size_t)MM * 256 * 2);
  u16* ic2b = (u16*)alloc((size_t)128 * 128 * 2);
  u16* ic3b = (u16*)alloc((size_t)256 * 256 * 2);
  float* qn2 = (float*)alloc((size_t)NQ * 4);
  float* qn3 = (float*)alloc((size_t)NQ * 4);
  float* mn2 = (float*)alloc((size_t)MM * 4);
  float* mn3 = (float*)alloc((size_t)MM * 4);
  float* kp2 = (float*)alloc((size_t)NQ * 8 * 5 * 4);
  float* kp3 = (float*)alloc((size_t)NQ * 8 * 5 * 4);
  float* mh2 = (float*)alloc((size_t)NQ * 4);
  float* mh3 = (float*)alloc((size_t)NQ * 4);

  k_prep<<<6488, 256, 0, stream>>>(q2, q3, mem2, mem3, icov2, icov3,
                                   qf2b, qf3b, m2t, m3t, ic2b, ic3b, mn2, mn3);

  // fused score (+q-norms, XCD-pinned splits) + co-dispatched maha
  k_score_f<<<1176, 256, 0, stream>>>(qf3b, m3t, mn3, kp3, qn3,
                                      qf2b, m2t, mn2, kp2, qn2,
                                      mean2, mean3, ic2b, ic3b, mh2, mh3);

  k_combine<<<NQ / 256, 256, 0, stream>>>(kp2, kp3, qn2, qn3, mh2, mh3, out);
  k_top10<<<16, 256, 0, stream>>>(out + 16, out);

  (void)in_sizes; (void)n_in; (void)out_size; (void)ws_size;
}